// Round 1
// baseline (636.223 us; speedup 1.0000x reference)
//
#include <hip/hip_runtime.h>

// Problem constants (from reference): B=32, S=128, H=512, K=8
#define BB 32
#define SS 128
#define HH 512
#define KC 8
#define NN 4096  // KC*HH

__device__ __forceinline__ float tanh_fast(float x) {
  // tanh(x) = 1 - 2/(e^{2x}+1); safe at +/-inf of expf (no NaN)
  float e = __expf(2.0f * x);
  return 1.0f - 2.0f / (e + 1.0f);
}

// C[M, 4096] = A[M, 512] @ G[512, 4096]; M = bc*128, all dims multiple of 128.
// fp32, 128x128 block tile, 256 threads, 8x8 per-thread micro-tile.
__global__ __launch_bounds__(256) void gemm_proj(
    const float* __restrict__ A,
    const float* __restrict__ G,
    float* __restrict__ C) {
  __shared__ float As[16][132];  // [k][m], padded
  __shared__ float Bs[16][132];  // [k][n], padded
  const int tid = threadIdx.x;
  const int tx = tid & 15, ty = tid >> 4;
  const int bn = blockIdx.x * 128;
  const int bm = blockIdx.y * 128;

  float acc[8][8];
#pragma unroll
  for (int i = 0; i < 8; ++i)
#pragma unroll
    for (int j = 0; j < 8; ++j) acc[i][j] = 0.0f;

  for (int k0 = 0; k0 < HH; k0 += 16) {
#pragma unroll
    for (int i = 0; i < 2; ++i) {
      int idx = tid + i * 256;       // 0..511
      int row = idx >> 2;            // 0..127 (m)
      int f = (idx & 3) << 2;        // 0,4,8,12 (k)
      float4 a4 = *(const float4*)&A[(size_t)(bm + row) * HH + k0 + f];
      As[f + 0][row] = a4.x; As[f + 1][row] = a4.y;
      As[f + 2][row] = a4.z; As[f + 3][row] = a4.w;
      int kr = idx >> 5;             // 0..15 (k)
      int nn = (idx & 31) << 2;      // 0..124 (n)
      *(float4*)&Bs[kr][nn] = *(const float4*)&G[(size_t)(k0 + kr) * NN + bn + nn];
    }
    __syncthreads();
#pragma unroll
    for (int kk = 0; kk < 16; ++kk) {
      float4 a0 = *(float4*)&As[kk][ty * 8];
      float4 a1 = *(float4*)&As[kk][ty * 8 + 4];
      float4 b0 = *(float4*)&Bs[kk][tx * 8];
      float4 b1 = *(float4*)&Bs[kk][tx * 8 + 4];
      float a[8] = {a0.x, a0.y, a0.z, a0.w, a1.x, a1.y, a1.z, a1.w};
      float b[8] = {b0.x, b0.y, b0.z, b0.w, b1.x, b1.y, b1.z, b1.w};
#pragma unroll
      for (int i = 0; i < 8; ++i)
#pragma unroll
        for (int j = 0; j < 8; ++j) acc[i][j] = fmaf(a[i], b[j], acc[i][j]);
    }
    __syncthreads();
  }

#pragma unroll
  for (int i = 0; i < 8; ++i) {
    size_t row = (size_t)(bm + ty * 8 + i);
    float4 c0 = make_float4(acc[i][0], acc[i][1], acc[i][2], acc[i][3]);
    float4 c1 = make_float4(acc[i][4], acc[i][5], acc[i][6], acc[i][7]);
    *(float4*)&C[row * NN + bn + tx * 8] = c0;
    *(float4*)&C[row * NN + bn + tx * 8 + 4] = c1;
  }
}

// One block per (batch b, 16-row s-tile).
// Stage 1: raw[s*8+k][t] = proj[b,s,k,:] . R[b,t,:]  (128x128x512 GEMM)
//   rows ordered s*8+k, thread (ty,tx) owns rows ty*8..+7 = all 8 k of s=ty,
//   cols tx*8..+7 -> tanh + v-weighted k-sum stays in registers.
// Stage 2: 16-lane shuffle softmax over t (128).
// Stage 3: out[s,:] = base[s,:] + attn[s,:] @ R[b]  (residual fused).
__global__ __launch_bounds__(256) void fused_attn(
    const float* __restrict__ proj,  // [bc*S, KC, HH] chunk-local
    const float* __restrict__ Rm,    // [bc, S, HH] right/context matrix
    const float* __restrict__ Bm,    // [bc, S, HH] residual base
    const float* __restrict__ v,     // [KC]
    float* __restrict__ outp) {      // [bc, S, HH]
  __shared__ float Ps[32][132];      // [g][row s*8+k]
  __shared__ float Rs[32][132];      // [g][t]
  __shared__ float attnS[16][132];   // [s][t]
  const int tid = threadIdx.x;
  const int tx = tid & 15, ty = tid >> 4;
  const int b = blockIdx.y;
  const int s0 = blockIdx.x * 16;
  const size_t pbase = ((size_t)b * SS + s0) * (KC * HH);
  const size_t rbase = (size_t)b * SS * HH;

  float acc[8][8];
#pragma unroll
  for (int i = 0; i < 8; ++i)
#pragma unroll
    for (int j = 0; j < 8; ++j) acc[i][j] = 0.0f;

  for (int g0 = 0; g0 < HH; g0 += 32) {
#pragma unroll
    for (int i = 0; i < 4; ++i) {
      int idx = tid + i * 256;   // 0..1023
      int row = idx >> 3;        // 0..127
      int f = (idx & 7) << 2;    // 0..28
      float4 p4 = *(const float4*)&proj[pbase + (size_t)row * HH + g0 + f];
      Ps[f + 0][row] = p4.x; Ps[f + 1][row] = p4.y;
      Ps[f + 2][row] = p4.z; Ps[f + 3][row] = p4.w;
      float4 r4 = *(const float4*)&Rm[rbase + (size_t)row * HH + g0 + f];
      Rs[f + 0][row] = r4.x; Rs[f + 1][row] = r4.y;
      Rs[f + 2][row] = r4.z; Rs[f + 3][row] = r4.w;
    }
    __syncthreads();
#pragma unroll
    for (int gg = 0; gg < 32; ++gg) {
      float4 a0 = *(float4*)&Ps[gg][ty * 8];
      float4 a1 = *(float4*)&Ps[gg][ty * 8 + 4];
      float4 b0 = *(float4*)&Rs[gg][tx * 8];
      float4 b1 = *(float4*)&Rs[gg][tx * 8 + 4];
      float a[8] = {a0.x, a0.y, a0.z, a0.w, a1.x, a1.y, a1.z, a1.w};
      float bj[8] = {b0.x, b0.y, b0.z, b0.w, b1.x, b1.y, b1.z, b1.w};
#pragma unroll
      for (int i = 0; i < 8; ++i)
#pragma unroll
        for (int j = 0; j < 8; ++j) acc[i][j] = fmaf(a[i], bj[j], acc[i][j]);
    }
    __syncthreads();
  }

  // k-combine: score[t_j] = sum_k v[k] * tanh(raw[k][t_j]); acc row i == k
  float vk[KC];
#pragma unroll
  for (int k = 0; k < KC; ++k) vk[k] = v[k];
  float sc[8];
#pragma unroll
  for (int j = 0; j < 8; ++j) {
    float s = 0.0f;
#pragma unroll
    for (int k = 0; k < KC; ++k) s = fmaf(vk[k], tanh_fast(acc[k][j]), s);
    sc[j] = s;
  }

  // softmax over t: this thread holds t = tx*8..tx*8+7 for row s = ty;
  // the 16 threads of a row are contiguous lanes -> width-16 shuffles.
  float mx = sc[0];
#pragma unroll
  for (int j = 1; j < 8; ++j) mx = fmaxf(mx, sc[j]);
#pragma unroll
  for (int off = 1; off < 16; off <<= 1) mx = fmaxf(mx, __shfl_xor(mx, off, 16));
  float p[8], ssum = 0.0f;
#pragma unroll
  for (int j = 0; j < 8; ++j) { p[j] = __expf(sc[j] - mx); ssum += p[j]; }
#pragma unroll
  for (int off = 1; off < 16; off <<= 1) ssum += __shfl_xor(ssum, off, 16);
  float inv = 1.0f / ssum;
#pragma unroll
  for (int j = 0; j < 8; ++j) attnS[ty][tx * 8 + j] = p[j] * inv;
  __syncthreads();

  // out[s, h] = base[s, h] + sum_t attn[s][t] * R[t, h]; h = tid and tid+256
  float oa[16], ob[16];
#pragma unroll
  for (int s = 0; s < 16; ++s) { oa[s] = 0.0f; ob[s] = 0.0f; }
  for (int t0 = 0; t0 < SS; t0 += 4) {
    float r0[4], r1[4];
#pragma unroll
    for (int u = 0; u < 4; ++u) {
      r0[u] = Rm[rbase + (size_t)(t0 + u) * HH + tid];
      r1[u] = Rm[rbase + (size_t)(t0 + u) * HH + tid + 256];
    }
#pragma unroll
    for (int s = 0; s < 16; ++s) {
      float4 a4 = *(float4*)&attnS[s][t0];
      oa[s] = fmaf(a4.x, r0[0], oa[s]);
      oa[s] = fmaf(a4.y, r0[1], oa[s]);
      oa[s] = fmaf(a4.z, r0[2], oa[s]);
      oa[s] = fmaf(a4.w, r0[3], oa[s]);
      ob[s] = fmaf(a4.x, r1[0], ob[s]);
      ob[s] = fmaf(a4.y, r1[1], ob[s]);
      ob[s] = fmaf(a4.z, r1[2], ob[s]);
      ob[s] = fmaf(a4.w, r1[3], ob[s]);
    }
  }
  const size_t obase = ((size_t)b * SS + s0) * HH;
#pragma unroll
  for (int s = 0; s < 16; ++s) {
    size_t r = obase + (size_t)s * HH + tid;
    outp[r] = Bm[r] + oa[s];
    outp[r + 256] = Bm[r + 256] + ob[s];
  }
}

extern "C" void kernel_launch(void* const* d_in, const int* in_sizes, int n_in,
                              void* d_out, int out_size, void* d_ws, size_t ws_size,
                              hipStream_t stream) {
  const float* A  = (const float*)d_in[0];  // aspect_hidden  [B,S,H]
  const float* P  = (const float*)d_in[1];  // polarity_hidden [B,S,H]
  const float* G1 = (const float*)d_in[2];  // G_aspect_polarity [H,K,H]
  const float* G2 = (const float*)d_in[3];  // G_polarity_aspect [H,K,H]
  const float* v1 = (const float*)d_in[4];  // [K]
  const float* v2 = (const float*)d_in[5];  // [K]
  float* out1 = (float*)d_out;                       // aspect_out
  float* out2 = out1 + (size_t)BB * SS * HH;         // polarity_out
  float* proj = (float*)d_ws;

  // proj chunk: bc batches -> bc * S * K * H floats (2 MB per batch)
  const size_t perBatch = (size_t)SS * KC * HH * sizeof(float);
  int Bc = (int)(ws_size / perBatch);
  if (Bc < 1) Bc = 1;
  if (Bc > BB) Bc = BB;

  for (int b0 = 0; b0 < BB; b0 += Bc) {
    int bc = (Bc < BB - b0) ? Bc : (BB - b0);
    size_t off = (size_t)b0 * SS * HH;
    dim3 gg(NN / 128, (unsigned)bc);   // (bc*S)/128 == bc
    dim3 ga(SS / 16, (unsigned)bc);
    // Branch 1: proj = A @ G1; scores vs P; out1 = A + attn @ P
    gemm_proj<<<gg, 256, 0, stream>>>(A + off, G1, proj);
    fused_attn<<<ga, 256, 0, stream>>>(proj, P + off, A + off, v1, out1 + off);
    // Branch 2: proj = A @ G2; scores vs A (faithful to source); out2 = P + attn @ A
    gemm_proj<<<gg, 256, 0, stream>>>(A + off, G2, proj);
    fused_attn<<<ga, 256, 0, stream>>>(proj, A + off, P + off, v2, out2 + off);
  }
}

// Round 2
// 302.276 us; speedup vs baseline: 2.1048x; 2.1048x over previous
//
#include <hip/hip_runtime.h>

// Problem constants: B=32, S=128, H=512, K=8
#define BB 32
#define SS 128
#define HH 512
#define KC 8
#define NN 4096  // KC*HH

typedef __attribute__((ext_vector_type(8))) short bf16x8;
typedef __attribute__((ext_vector_type(4))) float f32x4;

__device__ __forceinline__ unsigned short f2bf(float f) {
  unsigned int u = __float_as_uint(f);
  u += 0x7fffu + ((u >> 16) & 1u);   // round-to-nearest-even
  return (unsigned short)(u >> 16);
}
__device__ __forceinline__ float bf2f(unsigned short h) {
  return __uint_as_float(((unsigned int)h) << 16);
}
__device__ __forceinline__ float tanh_fast(float x) {
  float e = __expf(2.0f * x);
  return 1.0f - 2.0f / (e + 1.0f);
}
__device__ __forceinline__ void async16(const void* g, void* lds) {
  __builtin_amdgcn_global_load_lds(
      (const __attribute__((address_space(1))) unsigned int*)g,
      (__attribute__((address_space(3))) unsigned int*)lds, 16, 0, 0);
}

// ---- conversion kernels ---------------------------------------------------
// fp32 -> (hi, lo) bf16 split. n multiple of 1024.
__global__ __launch_bounds__(256) void convert_split(
    const float* __restrict__ x, unsigned short* __restrict__ hi,
    unsigned short* __restrict__ lo, int n) {
  int i = (blockIdx.x * 256 + threadIdx.x) * 4;
  if (i >= n) return;
  float4 f = *(const float4*)&x[i];
  ushort4 h, l;
  h.x = f2bf(f.x); l.x = f2bf(f.x - bf2f(h.x));
  h.y = f2bf(f.y); l.y = f2bf(f.y - bf2f(h.y));
  h.z = f2bf(f.z); l.z = f2bf(f.z - bf2f(h.z));
  h.w = f2bf(f.w); l.w = f2bf(f.w - bf2f(h.w));
  *(ushort4*)&hi[i] = h;
  *(ushort4*)&lo[i] = l;
}

// G [512, 4096] fp32 -> G^T [4096, 512] (hi, lo) bf16.  32x32 tiles.
__global__ __launch_bounds__(256) void convert_transpose(
    const float* __restrict__ G, unsigned short* __restrict__ hiT,
    unsigned short* __restrict__ loT) {
  __shared__ float t[32][33];
  const int bx = blockIdx.x * 32;  // n
  const int by = blockIdx.y * 32;  // k
  const int tx = threadIdx.x & 31, ty = threadIdx.x >> 5;  // ty 0..7
#pragma unroll
  for (int r = 0; r < 4; ++r)
    t[ty + r * 8][tx] = G[(size_t)(by + ty + r * 8) * NN + bx + tx];
  __syncthreads();
#pragma unroll
  for (int r = 0; r < 4; ++r) {
    float f = t[tx][ty + r * 8];           // t[k_loc][n_loc]
    size_t o = (size_t)(bx + ty + r * 8) * HH + by + tx;
    unsigned short h = f2bf(f);
    hiT[o] = h;
    loT[o] = f2bf(f - bf2f(h));
  }
}

// ---- shared 128x128x512 split-bf16 MFMA core ------------------------------
// A (hi/lo): [>=128, 512] row-major, pre-offset to block row base.
// B (hi/lo): [>=128, 512] row-major = B^T layout, pre-offset to block col base.
// sm: 16384 ushorts (32 KB): [Ahi|Alo|Bhi|Blo] tiles, each [128][32].
// acc[i][j]: 16x16 C frags; wave (wm,wn) covers rows wm*64+i*16, cols wn*64+j*16.
__device__ __forceinline__ void mm128_core(
    const unsigned short* __restrict__ Ah, const unsigned short* __restrict__ Al,
    const unsigned short* __restrict__ Bh, const unsigned short* __restrict__ Bl,
    unsigned short* sm, f32x4 acc[4][4]) {
  const int tid = threadIdx.x;
  const int w = tid >> 6, L = tid & 63;
  const int wm = w >> 1, wn = w & 1;
  char* smb = (char*)sm;
  // staging: wave w stages rows [w*32, w*32+32) of each tile; lane L -> row L>>2,
  // 16B chunk (L&3). LDS dest = uniform base + lane*16 => row-major [row][32k].
  const int srow = w * 32 + (L >> 2);
  const int scol = (L & 3) * 8;
  const unsigned short* pAh = Ah + (size_t)srow * HH + scol;
  const unsigned short* pAl = Al + (size_t)srow * HH + scol;
  const unsigned short* pBh = Bh + (size_t)srow * HH + scol;
  const unsigned short* pBl = Bl + (size_t)srow * HH + scol;
  const unsigned lbase = (unsigned)w * 2048;  // bytes within a tile
  // fragment read offsets (ushort units), constant across K-loop
  const int ar = (wm * 64 + (L & 15)) * 32 + (L >> 4) * 8;
  const int br = (wn * 64 + (L & 15)) * 32 + (L >> 4) * 8;

  for (int kt = 0; kt < 16; ++kt) {
    const int k0 = kt * 32;
    async16(pAh + k0, smb + lbase);
    async16(pAh + k0 + 16 * HH, smb + lbase + 1024);
    async16(pAl + k0, smb + 8192 + lbase);
    async16(pAl + k0 + 16 * HH, smb + 8192 + lbase + 1024);
    async16(pBh + k0, smb + 16384 + lbase);
    async16(pBh + k0 + 16 * HH, smb + 16384 + lbase + 1024);
    async16(pBl + k0, smb + 24576 + lbase);
    async16(pBl + k0 + 16 * HH, smb + 24576 + lbase + 1024);
    __syncthreads();
    bf16x8 ah[4], al[4], bh[4], bl[4];
#pragma unroll
    for (int i = 0; i < 4; ++i) {
      ah[i] = *(const bf16x8*)&sm[ar + i * 512];
      al[i] = *(const bf16x8*)&sm[4096 + ar + i * 512];
      bh[i] = *(const bf16x8*)&sm[8192 + br + i * 512];
      bl[i] = *(const bf16x8*)&sm[12288 + br + i * 512];
    }
#pragma unroll
    for (int i = 0; i < 4; ++i)
#pragma unroll
      for (int j = 0; j < 4; ++j) {
        acc[i][j] = __builtin_amdgcn_mfma_f32_16x16x32_bf16(ah[i], bh[j], acc[i][j], 0, 0, 0);
        acc[i][j] = __builtin_amdgcn_mfma_f32_16x16x32_bf16(ah[i], bl[j], acc[i][j], 0, 0, 0);
        acc[i][j] = __builtin_amdgcn_mfma_f32_16x16x32_bf16(al[i], bh[j], acc[i][j], 0, 0, 0);
      }
    __syncthreads();
  }
}

// ---- proj GEMM: C[M,4096] = A[M,512] @ G[512,4096], split output ----------
__global__ __launch_bounds__(256) void gemm_split(
    const unsigned short* __restrict__ Ahi, const unsigned short* __restrict__ Alo,
    const unsigned short* __restrict__ BThi, const unsigned short* __restrict__ BTlo,
    unsigned short* __restrict__ Chi, unsigned short* __restrict__ Clo) {
  __shared__ unsigned short sm[16384];
  const int bn = blockIdx.x * 128, bm = blockIdx.y * 128;
  f32x4 acc[4][4];
#pragma unroll
  for (int i = 0; i < 4; ++i)
#pragma unroll
    for (int j = 0; j < 4; ++j) acc[i][j] = (f32x4)(0.0f);
  mm128_core(Ahi + (size_t)bm * HH, Alo + (size_t)bm * HH,
             BThi + (size_t)bn * HH, BTlo + (size_t)bn * HH, sm, acc);
  const int tid = threadIdx.x, L = tid & 63, w = tid >> 6;
  const int wm = w >> 1, wn = w & 1;
  const int q = L >> 4, c = L & 15;
#pragma unroll
  for (int i = 0; i < 4; ++i)
#pragma unroll
    for (int j = 0; j < 4; ++j) {
      const int row = bm + wm * 64 + i * 16 + q * 4;
      const int col = bn + wn * 64 + j * 16 + c;
#pragma unroll
      for (int r = 0; r < 4; ++r) {
        float f = acc[i][j][r];
        unsigned short h = f2bf(f);
        size_t o = (size_t)(row + r) * NN + col;
        Chi[o] = h;
        Clo[o] = f2bf(f - bf2f(h));
      }
    }
}

// ---- fused score GEMM + tanh/k-combine + softmax + PV + residual ----------
// Block (rt, b): proj rows [b*1024 + rt*128, +128) -> s in [rt*16, rt*16+16),
// all 128 t. Row ordering within tile: row = s_loc*8 + k.
__global__ __launch_bounds__(256) void attn_fused(
    const unsigned short* __restrict__ Pjh, const unsigned short* __restrict__ Pjl,
    const unsigned short* __restrict__ Rhi, const unsigned short* __restrict__ Rlo,
    const float* __restrict__ Rm,   // right matrix fp32 [bc,128,512]
    const float* __restrict__ Bm,   // residual base fp32
    const float* __restrict__ v,    // [8]
    float* __restrict__ outp) {
  __shared__ unsigned short sm[16384];
  __shared__ float scoresS[16][132];
  const int b = blockIdx.y, rt = blockIdx.x;
  f32x4 acc[4][4];
#pragma unroll
  for (int i = 0; i < 4; ++i)
#pragma unroll
    for (int j = 0; j < 4; ++j) acc[i][j] = (f32x4)(0.0f);
  mm128_core(Pjh + ((size_t)b * 1024 + (size_t)rt * 128) * HH,
             Pjl + ((size_t)b * 1024 + (size_t)rt * 128) * HH,
             Rhi + (size_t)b * SS * HH, Rlo + (size_t)b * SS * HH, sm, acc);

  const int tid = threadIdx.x, L = tid & 63, w = tid >> 6;
  const int wm = w >> 1, wn = w & 1;
  const int q = L >> 4, c = L & 15;
  float vk[KC];
#pragma unroll
  for (int k = 0; k < KC; ++k) vk[k] = v[k];
  // C frag row = local (s,k): k = (q&1)*4 + r, s_loc = wm*8 + i*2 + (q>>1)
#pragma unroll
  for (int i = 0; i < 4; ++i)
#pragma unroll
    for (int j = 0; j < 4; ++j) {
      float part = 0.0f;
#pragma unroll
      for (int r = 0; r < 4; ++r)
        part = fmaf(vk[(q & 1) * 4 + r], tanh_fast(acc[i][j][r]), part);
      part += __shfl_xor(part, 16);  // combine k halves (q ^ 1)
      if ((q & 1) == 0)
        scoresS[wm * 8 + i * 2 + (q >> 1)][wn * 64 + j * 16 + c] = part;
    }
  __syncthreads();

  // softmax over t (128), 16 threads per s-row
  const int tx = tid & 15, ty = tid >> 4;
  float sc[8];
#pragma unroll
  for (int j = 0; j < 8; ++j) sc[j] = scoresS[ty][tx * 8 + j];
  float mx = sc[0];
#pragma unroll
  for (int j = 1; j < 8; ++j) mx = fmaxf(mx, sc[j]);
#pragma unroll
  for (int off = 1; off < 16; off <<= 1) mx = fmaxf(mx, __shfl_xor(mx, off, 16));
  float p[8], ssum = 0.0f;
#pragma unroll
  for (int j = 0; j < 8; ++j) { p[j] = __expf(sc[j] - mx); ssum += p[j]; }
#pragma unroll
  for (int off = 1; off < 16; off <<= 1) ssum += __shfl_xor(ssum, off, 16);
  float inv = 1.0f / ssum;
  __syncthreads();
#pragma unroll
  for (int j = 0; j < 8; ++j) scoresS[ty][tx * 8 + j] = p[j] * inv;
  __syncthreads();

  // out[s,h] = base[s,h] + sum_t attn[s][t] * R[t,h]; h = tid, tid+256
  const size_t rbase = (size_t)b * SS * HH;
  float oa[16], ob[16];
#pragma unroll
  for (int s = 0; s < 16; ++s) { oa[s] = 0.0f; ob[s] = 0.0f; }
  for (int t0 = 0; t0 < SS; t0 += 4) {
    float r0[4], r1[4];
#pragma unroll
    for (int u = 0; u < 4; ++u) {
      r0[u] = Rm[rbase + (size_t)(t0 + u) * HH + tid];
      r1[u] = Rm[rbase + (size_t)(t0 + u) * HH + tid + 256];
    }
#pragma unroll
    for (int s = 0; s < 16; ++s) {
      float4 a4 = *(float4*)&scoresS[s][t0];
      oa[s] = fmaf(a4.x, r0[0], oa[s]);
      oa[s] = fmaf(a4.y, r0[1], oa[s]);
      oa[s] = fmaf(a4.z, r0[2], oa[s]);
      oa[s] = fmaf(a4.w, r0[3], oa[s]);
      ob[s] = fmaf(a4.x, r1[0], ob[s]);
      ob[s] = fmaf(a4.y, r1[1], ob[s]);
      ob[s] = fmaf(a4.z, r1[2], ob[s]);
      ob[s] = fmaf(a4.w, r1[3], ob[s]);
    }
  }
  const size_t obase = ((size_t)b * SS + (size_t)rt * 16) * HH;
#pragma unroll
  for (int s = 0; s < 16; ++s) {
    size_t rr = obase + (size_t)s * HH + tid;
    outp[rr] = Bm[rr] + oa[s];
    outp[rr + 256] = Bm[rr + 256] + ob[s];
  }
}

extern "C" void kernel_launch(void* const* d_in, const int* in_sizes, int n_in,
                              void* d_out, int out_size, void* d_ws, size_t ws_size,
                              hipStream_t stream) {
  const float* A  = (const float*)d_in[0];
  const float* P  = (const float*)d_in[1];
  const float* G1 = (const float*)d_in[2];
  const float* G2 = (const float*)d_in[3];
  const float* v1 = (const float*)d_in[4];
  const float* v2 = (const float*)d_in[5];
  float* out1 = (float*)d_out;
  float* out2 = out1 + (size_t)BB * SS * HH;

  const size_t NA = (size_t)BB * SS * HH;  // 2M elements
  const size_t NG = (size_t)HH * KC * HH;  // 2M elements
  unsigned short* Ahi = (unsigned short*)d_ws;
  unsigned short* Alo = Ahi + NA;
  unsigned short* Phi = Alo + NA;
  unsigned short* Plo = Phi + NA;
  unsigned short* G1h = Plo + NA;
  unsigned short* G1l = G1h + NG;
  unsigned short* G2h = G1l + NG;
  unsigned short* G2l = G2h + NG;
  unsigned short* prjH = G2l + NG;
  const size_t fixedBytes = (4 * NA + 4 * NG) * sizeof(unsigned short);  // 32 MB
  const size_t perB = (size_t)SS * NN * 2 * sizeof(unsigned short);      // 2 MB/batch
  size_t rem = ws_size > fixedBytes ? ws_size - fixedBytes : 0;
  int Bc = (int)(rem / perB);
  if (Bc < 1) Bc = 1;
  if (Bc > BB) Bc = BB;
  unsigned short* prjL = prjH + (size_t)Bc * SS * NN;

  convert_split<<<(unsigned)(NA / 1024), 256, 0, stream>>>(A, Ahi, Alo, (int)NA);
  convert_split<<<(unsigned)(NA / 1024), 256, 0, stream>>>(P, Phi, Plo, (int)NA);
  convert_transpose<<<dim3(NN / 32, HH / 32), 256, 0, stream>>>(G1, G1h, G1l);
  convert_transpose<<<dim3(NN / 32, HH / 32), 256, 0, stream>>>(G2, G2h, G2l);

  for (int b0 = 0; b0 < BB; b0 += Bc) {
    int bc = (Bc < BB - b0) ? Bc : (BB - b0);
    size_t off = (size_t)b0 * SS * HH;  // element offset (rows*512)
    // Branch 1: proj = A@G1; scores vs P; out1 = A + attn @ P
    gemm_split<<<dim3(NN / 128, bc), 256, 0, stream>>>(Ahi + off, Alo + off, G1h, G1l, prjH, prjL);
    attn_fused<<<dim3(8, bc), 256, 0, stream>>>(prjH, prjL, Phi + off, Plo + off,
                                                P + off, A + off, v1, out1 + off);
    // Branch 2: proj = A@G2; scores vs A (faithful); out2 = P + attn @ A
    gemm_split<<<dim3(NN / 128, bc), 256, 0, stream>>>(Ahi + off, Alo + off, G2h, G2l, prjH, prjL);
    attn_fused<<<dim3(8, bc), 256, 0, stream>>>(prjH, prjL, Ahi + off, Alo + off,
                                                A + off, P + off, v2, out2 + off);
  }
}

// Round 3
// 293.353 us; speedup vs baseline: 2.1688x; 1.0304x over previous
//
#include <hip/hip_runtime.h>

// Problem constants: B=32, S=128, H=512, K=8
#define BB 32
#define SS 128
#define HH 512
#define KC 8
#define NN 4096  // KC*HH

typedef __attribute__((ext_vector_type(8))) short bf16x8;
typedef __attribute__((ext_vector_type(4))) float f32x4;

__device__ __forceinline__ unsigned short f2bf(float f) {
  unsigned int u = __float_as_uint(f);
  u += 0x7fffu + ((u >> 16) & 1u);   // round-to-nearest-even
  return (unsigned short)(u >> 16);
}
__device__ __forceinline__ float bf2f(unsigned short h) {
  return __uint_as_float(((unsigned int)h) << 16);
}
__device__ __forceinline__ float tanh_fast(float x) {
  float e = __expf(2.0f * x);
  return 1.0f - 2.0f / (e + 1.0f);
}
__device__ __forceinline__ void async16(const void* g, void* lds) {
  __builtin_amdgcn_global_load_lds(
      (const __attribute__((address_space(1))) unsigned int*)g,
      (__attribute__((address_space(3))) unsigned int*)lds, 16, 0, 0);
}

// ---- conversion kernels ---------------------------------------------------
__global__ __launch_bounds__(256) void convert_split(
    const float* __restrict__ x, unsigned short* __restrict__ hi,
    unsigned short* __restrict__ lo, int n) {
  int i = (blockIdx.x * 256 + threadIdx.x) * 4;
  if (i >= n) return;
  float4 f = *(const float4*)&x[i];
  ushort4 h, l;
  h.x = f2bf(f.x); l.x = f2bf(f.x - bf2f(h.x));
  h.y = f2bf(f.y); l.y = f2bf(f.y - bf2f(h.y));
  h.z = f2bf(f.z); l.z = f2bf(f.z - bf2f(h.z));
  h.w = f2bf(f.w); l.w = f2bf(f.w - bf2f(h.w));
  *(ushort4*)&hi[i] = h;
  *(ushort4*)&lo[i] = l;
}

// G [512, 4096] fp32 -> G^T [4096, 512] (hi, lo) bf16.
__global__ __launch_bounds__(256) void convert_transpose(
    const float* __restrict__ G, unsigned short* __restrict__ hiT,
    unsigned short* __restrict__ loT) {
  __shared__ float t[32][33];
  const int bx = blockIdx.x * 32;  // n
  const int by = blockIdx.y * 32;  // k
  const int tx = threadIdx.x & 31, ty = threadIdx.x >> 5;
#pragma unroll
  for (int r = 0; r < 4; ++r)
    t[ty + r * 8][tx] = G[(size_t)(by + ty + r * 8) * NN + bx + tx];
  __syncthreads();
#pragma unroll
  for (int r = 0; r < 4; ++r) {
    float f = t[tx][ty + r * 8];
    size_t o = (size_t)(bx + ty + r * 8) * HH + by + tx;
    unsigned short h = f2bf(f);
    hiT[o] = h;
    loT[o] = f2bf(f - bf2f(h));
  }
}

// X [B,S,H] fp32 -> X^T [B,H,S] (hi, lo) bf16 (per-batch transpose).
__global__ __launch_bounds__(256) void convert_transpose_b(
    const float* __restrict__ X, unsigned short* __restrict__ hiT,
    unsigned short* __restrict__ loT) {
  __shared__ float t[32][33];
  const int h0 = blockIdx.x * 32;
  const int s0 = blockIdx.y * 32;
  const size_t b = blockIdx.z;
  const int tx = threadIdx.x & 31, ty = threadIdx.x >> 5;
#pragma unroll
  for (int r = 0; r < 4; ++r)
    t[ty + r * 8][tx] = X[b * (SS * HH) + (size_t)(s0 + ty + r * 8) * HH + h0 + tx];
  __syncthreads();
#pragma unroll
  for (int r = 0; r < 4; ++r) {
    float f = t[tx][ty + r * 8];   // t[s_loc][h_loc] read transposed
    size_t o = b * (SS * HH) + (size_t)(h0 + ty + r * 8) * SS + s0 + tx;
    unsigned short h = f2bf(f);
    hiT[o] = h;
    loT[o] = f2bf(f - bf2f(h));
  }
}

// ---- shared 128x128xK split-bf16 MFMA core --------------------------------
// A (hi/lo): [>=128, SA] row-major; B (hi/lo): [>=128, SB] row-major (B^T).
// sm: 16384 ushorts: [Ahi|Alo|Bhi|Blo] tiles, each [128][32].
// acc[i][j]: 16x16 C frags; wave (wm,wn) covers rows wm*64+i*16, cols wn*64+j*16.
template <int SA, int SB, int KIT>
__device__ __forceinline__ void mm128_core(
    const unsigned short* __restrict__ Ah, const unsigned short* __restrict__ Al,
    const unsigned short* __restrict__ Bh, const unsigned short* __restrict__ Bl,
    unsigned short* sm, f32x4 acc[4][4]) {
  const int tid = threadIdx.x;
  const int w = tid >> 6, L = tid & 63;
  const int wm = w >> 1, wn = w & 1;
  char* smb = (char*)sm;
  const int srow = w * 32 + (L >> 2);
  const int scol = (L & 3) * 8;
  const unsigned short* pAh = Ah + (size_t)srow * SA + scol;
  const unsigned short* pAl = Al + (size_t)srow * SA + scol;
  const unsigned short* pBh = Bh + (size_t)srow * SB + scol;
  const unsigned short* pBl = Bl + (size_t)srow * SB + scol;
  const unsigned lbase = (unsigned)w * 2048;
  const int ar = (wm * 64 + (L & 15)) * 32 + (L >> 4) * 8;
  const int br = (wn * 64 + (L & 15)) * 32 + (L >> 4) * 8;

  for (int kt = 0; kt < KIT; ++kt) {
    const int k0 = kt * 32;
    async16(pAh + k0, smb + lbase);
    async16(pAh + k0 + 16 * SA, smb + lbase + 1024);
    async16(pAl + k0, smb + 8192 + lbase);
    async16(pAl + k0 + 16 * SA, smb + 8192 + lbase + 1024);
    async16(pBh + k0, smb + 16384 + lbase);
    async16(pBh + k0 + 16 * SB, smb + 16384 + lbase + 1024);
    async16(pBl + k0, smb + 24576 + lbase);
    async16(pBl + k0 + 16 * SB, smb + 24576 + lbase + 1024);
    __syncthreads();
    bf16x8 ah[4], al[4], bh[4], bl[4];
#pragma unroll
    for (int i = 0; i < 4; ++i) {
      ah[i] = *(const bf16x8*)&sm[ar + i * 512];
      al[i] = *(const bf16x8*)&sm[4096 + ar + i * 512];
      bh[i] = *(const bf16x8*)&sm[8192 + br + i * 512];
      bl[i] = *(const bf16x8*)&sm[12288 + br + i * 512];
    }
#pragma unroll
    for (int i = 0; i < 4; ++i)
#pragma unroll
      for (int j = 0; j < 4; ++j) {
        acc[i][j] = __builtin_amdgcn_mfma_f32_16x16x32_bf16(ah[i], bh[j], acc[i][j], 0, 0, 0);
        acc[i][j] = __builtin_amdgcn_mfma_f32_16x16x32_bf16(ah[i], bl[j], acc[i][j], 0, 0, 0);
        acc[i][j] = __builtin_amdgcn_mfma_f32_16x16x32_bf16(al[i], bh[j], acc[i][j], 0, 0, 0);
      }
    __syncthreads();
  }
}

// ---- proj GEMM (both branches): C[M,4096] = A[M,512] @ G[512,4096] --------
__global__ __launch_bounds__(256) void gemm_split(
    const unsigned short* __restrict__ Ahi, const unsigned short* __restrict__ Alo,
    const unsigned short* __restrict__ G1h, const unsigned short* __restrict__ G1l,
    const unsigned short* __restrict__ G2h, const unsigned short* __restrict__ G2l,
    unsigned short* __restrict__ C1h, unsigned short* __restrict__ C1l,
    unsigned short* __restrict__ C2h, unsigned short* __restrict__ C2l) {
  __shared__ unsigned short sm[16384];
  const int bn = blockIdx.x * 128, bm = blockIdx.y * 128, brx = blockIdx.z;
  const unsigned short* Bh = (brx ? G2h : G1h) + (size_t)bn * HH;
  const unsigned short* Bl = (brx ? G2l : G1l) + (size_t)bn * HH;
  unsigned short* Ch = brx ? C2h : C1h;
  unsigned short* Cl = brx ? C2l : C1l;
  f32x4 acc[4][4];
#pragma unroll
  for (int i = 0; i < 4; ++i)
#pragma unroll
    for (int j = 0; j < 4; ++j) acc[i][j] = (f32x4)(0.0f);
  mm128_core<HH, HH, 16>(Ahi + (size_t)bm * HH, Alo + (size_t)bm * HH, Bh, Bl, sm, acc);
  const int tid = threadIdx.x, L = tid & 63, w = tid >> 6;
  const int wm = w >> 1, wn = w & 1;
  const int q = L >> 4, c = L & 15;
#pragma unroll
  for (int i = 0; i < 4; ++i)
#pragma unroll
    for (int j = 0; j < 4; ++j) {
      const int row = bm + wm * 64 + i * 16 + q * 4;
      const int col = bn + wn * 64 + j * 16 + c;
#pragma unroll
      for (int r = 0; r < 4; ++r) {
        float f = acc[i][j][r];
        unsigned short h = f2bf(f);
        size_t o = (size_t)(row + r) * NN + col;
        Ch[o] = h;
        Cl[o] = f2bf(f - bf2f(h));
      }
    }
}

// ---- score GEMM + tanh/k-combine + softmax -> attn weights (bf16 split) ---
// Block (rt, b, br): proj rows [b*1024 + rt*128, +128) = 16 s x 8 k; all 128 t.
__global__ __launch_bounds__(256) void attn_score(
    const unsigned short* __restrict__ P1h, const unsigned short* __restrict__ P1l,
    const unsigned short* __restrict__ P2h, const unsigned short* __restrict__ P2l,
    const unsigned short* __restrict__ R1h, const unsigned short* __restrict__ R1l,
    const unsigned short* __restrict__ R2h, const unsigned short* __restrict__ R2l,
    const float* __restrict__ v1, const float* __restrict__ v2,
    unsigned short* __restrict__ attnH, unsigned short* __restrict__ attnL,
    int BcS) {
  __shared__ unsigned short sm[16384];
  __shared__ float scoresS[16][132];
  const int b = blockIdx.y, rt = blockIdx.x, brx = blockIdx.z;
  const unsigned short* Pjh = (brx ? P2h : P1h) + ((size_t)b * 1024 + (size_t)rt * 128) * HH;
  const unsigned short* Pjl = (brx ? P2l : P1l) + ((size_t)b * 1024 + (size_t)rt * 128) * HH;
  const unsigned short* Rh = (brx ? R2h : R1h) + (size_t)b * SS * HH;
  const unsigned short* Rl = (brx ? R2l : R1l) + (size_t)b * SS * HH;
  const float* v = brx ? v2 : v1;
  f32x4 acc[4][4];
#pragma unroll
  for (int i = 0; i < 4; ++i)
#pragma unroll
    for (int j = 0; j < 4; ++j) acc[i][j] = (f32x4)(0.0f);
  mm128_core<HH, HH, 16>(Pjh, Pjl, Rh, Rl, sm, acc);

  const int tid = threadIdx.x, L = tid & 63, w = tid >> 6;
  const int wm = w >> 1, wn = w & 1;
  const int q = L >> 4, c = L & 15;
  float vk[KC];
#pragma unroll
  for (int k = 0; k < KC; ++k) vk[k] = v[k];
  // C frag row = local (s,k): k = (q&1)*4 + r, s_loc = wm*8 + i*2 + (q>>1)
#pragma unroll
  for (int i = 0; i < 4; ++i)
#pragma unroll
    for (int j = 0; j < 4; ++j) {
      float part = 0.0f;
#pragma unroll
      for (int r = 0; r < 4; ++r)
        part = fmaf(vk[(q & 1) * 4 + r], tanh_fast(acc[i][j][r]), part);
      part += __shfl_xor(part, 16);  // combine k halves
      if ((q & 1) == 0)
        scoresS[wm * 8 + i * 2 + (q >> 1)][wn * 64 + j * 16 + c] = part;
    }
  __syncthreads();

  // softmax over t (128), 16 threads per s-row
  const int tx = tid & 15, ty = tid >> 4;
  float sc[8];
#pragma unroll
  for (int j = 0; j < 8; ++j) sc[j] = scoresS[ty][tx * 8 + j];
  float mx = sc[0];
#pragma unroll
  for (int j = 1; j < 8; ++j) mx = fmaxf(mx, sc[j]);
#pragma unroll
  for (int off = 1; off < 16; off <<= 1) mx = fmaxf(mx, __shfl_xor(mx, off, 16));
  float p[8], ssum = 0.0f;
#pragma unroll
  for (int j = 0; j < 8; ++j) { p[j] = __expf(sc[j] - mx); ssum += p[j]; }
#pragma unroll
  for (int off = 1; off < 16; off <<= 1) ssum += __shfl_xor(ssum, off, 16);
  float inv = 1.0f / ssum;

  // write attn weights bf16 hi/lo: row s = rt*16+ty, cols tx*8..+7
  float wgt[8];
  unsigned short hh[8], ll[8];
#pragma unroll
  for (int j = 0; j < 8; ++j) {
    wgt[j] = p[j] * inv;
    hh[j] = f2bf(wgt[j]);
    ll[j] = f2bf(wgt[j] - bf2f(hh[j]));
  }
  size_t abase = ((size_t)brx * BcS + b) * (SS * SS) + (size_t)(rt * 16 + ty) * SS + tx * 8;
  *(ushort4*)&attnH[abase]     = make_ushort4(hh[0], hh[1], hh[2], hh[3]);
  *(ushort4*)&attnH[abase + 4] = make_ushort4(hh[4], hh[5], hh[6], hh[7]);
  *(ushort4*)&attnL[abase]     = make_ushort4(ll[0], ll[1], ll[2], ll[3]);
  *(ushort4*)&attnL[abase + 4] = make_ushort4(ll[4], ll[5], ll[6], ll[7]);
}

// ---- PV + residual: out[b,s,h] = base[b,s,h] + attn[b] @ R[b] -------------
// Block (nb, b, br): all 128 s, h chunk nb*128..+127; K = t = 128.
__global__ __launch_bounds__(256) void pv_res(
    const unsigned short* __restrict__ attnH, const unsigned short* __restrict__ attnL,
    const unsigned short* __restrict__ PTh, const unsigned short* __restrict__ PTl,
    const unsigned short* __restrict__ ATh, const unsigned short* __restrict__ ATl,
    const float* __restrict__ Abase, const float* __restrict__ Pbase,
    float* __restrict__ out1, float* __restrict__ out2, int BcS) {
  __shared__ unsigned short sm[16384];
  const int n0 = blockIdx.x * 128;
  const int bb = blockIdx.y, brx = blockIdx.z;
  const unsigned short* Ah = attnH + ((size_t)brx * BcS + bb) * (SS * SS);
  const unsigned short* Al = attnL + ((size_t)brx * BcS + bb) * (SS * SS);
  const unsigned short* Bh = (brx ? ATh : PTh) + (size_t)bb * HH * SS + (size_t)n0 * SS;
  const unsigned short* Bl = (brx ? ATl : PTl) + (size_t)bb * HH * SS + (size_t)n0 * SS;
  const float* base = (brx ? Pbase : Abase) + (size_t)bb * SS * HH;
  float* outp = (brx ? out2 : out1) + (size_t)bb * SS * HH;
  f32x4 acc[4][4];
#pragma unroll
  for (int i = 0; i < 4; ++i)
#pragma unroll
    for (int j = 0; j < 4; ++j) acc[i][j] = (f32x4)(0.0f);
  mm128_core<SS, SS, 4>(Ah, Al, Bh, Bl, sm, acc);
  const int tid = threadIdx.x, L = tid & 63, w = tid >> 6;
  const int wm = w >> 1, wn = w & 1;
  const int q = L >> 4, c = L & 15;
#pragma unroll
  for (int i = 0; i < 4; ++i)
#pragma unroll
    for (int j = 0; j < 4; ++j) {
      const int row = wm * 64 + i * 16 + q * 4;   // s
      const int col = n0 + wn * 64 + j * 16 + c;  // h
#pragma unroll
      for (int r = 0; r < 4; ++r) {
        size_t o = (size_t)(row + r) * HH + col;
        outp[o] = base[o] + acc[i][j][r];
      }
    }
}

extern "C" void kernel_launch(void* const* d_in, const int* in_sizes, int n_in,
                              void* d_out, int out_size, void* d_ws, size_t ws_size,
                              hipStream_t stream) {
  const float* A  = (const float*)d_in[0];
  const float* P  = (const float*)d_in[1];
  const float* G1 = (const float*)d_in[2];
  const float* G2 = (const float*)d_in[3];
  const float* v1 = (const float*)d_in[4];
  const float* v2 = (const float*)d_in[5];
  float* out1 = (float*)d_out;
  float* out2 = out1 + (size_t)BB * SS * HH;

  const size_t NA = (size_t)BB * SS * HH;  // 2M
  const size_t NG = (size_t)HH * KC * HH;  // 2M
  unsigned short* Ahi = (unsigned short*)d_ws;
  unsigned short* Alo = Ahi + NA;
  unsigned short* Phi = Alo + NA;
  unsigned short* Plo = Phi + NA;
  unsigned short* G1h = Plo + NA;
  unsigned short* G1l = G1h + NG;
  unsigned short* G2h = G1l + NG;
  unsigned short* G2l = G2h + NG;
  unsigned short* ATh = G2l + NG;
  unsigned short* ATl = ATh + NA;
  unsigned short* PTh = ATl + NA;
  unsigned short* PTl = PTh + NA;
  unsigned short* dyn = PTl + NA;

  const size_t fixedBytes = (8 * NA + 4 * NG) * sizeof(unsigned short);  // 48 MB
  const size_t projPerB = (size_t)SS * NN;        // ushorts per batch per buffer
  const size_t attnPerB = (size_t)SS * SS;        // ushorts per batch per (buf,branch)
  const size_t perB = (4 * projPerB + 4 * attnPerB) * sizeof(unsigned short);
  size_t rem = ws_size > fixedBytes ? ws_size - fixedBytes : 0;
  int Bc = (int)(rem / perB);
  if (Bc < 1) Bc = 1;
  if (Bc > BB) Bc = BB;
  unsigned short* prjH1 = dyn;
  unsigned short* prjL1 = prjH1 + (size_t)Bc * projPerB;
  unsigned short* prjH2 = prjL1 + (size_t)Bc * projPerB;
  unsigned short* prjL2 = prjH2 + (size_t)Bc * projPerB;
  unsigned short* attnH = prjL2 + (size_t)Bc * projPerB;
  unsigned short* attnL = attnH + 2 * (size_t)Bc * attnPerB;

  convert_split<<<(unsigned)(NA / 1024), 256, 0, stream>>>(A, Ahi, Alo, (int)NA);
  convert_split<<<(unsigned)(NA / 1024), 256, 0, stream>>>(P, Phi, Plo, (int)NA);
  convert_transpose<<<dim3(NN / 32, HH / 32), 256, 0, stream>>>(G1, G1h, G1l);
  convert_transpose<<<dim3(NN / 32, HH / 32), 256, 0, stream>>>(G2, G2h, G2l);
  convert_transpose_b<<<dim3(HH / 32, SS / 32, BB), 256, 0, stream>>>(A, ATh, ATl);
  convert_transpose_b<<<dim3(HH / 32, SS / 32, BB), 256, 0, stream>>>(P, PTh, PTl);

  for (int b0 = 0; b0 < BB; b0 += Bc) {
    int bc = (Bc < BB - b0) ? Bc : (BB - b0);
    size_t off = (size_t)b0 * SS * HH;  // element offset (65536/batch, both layouts)
    gemm_split<<<dim3(NN / 128, bc, 2), 256, 0, stream>>>(
        Ahi + off, Alo + off, G1h, G1l, G2h, G2l,
        prjH1, prjL1, prjH2, prjL2);
    attn_score<<<dim3(8, bc, 2), 256, 0, stream>>>(
        prjH1, prjL1, prjH2, prjL2,
        Phi + off, Plo + off, Ahi + off, Alo + off,
        v1, v2, attnH, attnL, Bc);
    pv_res<<<dim3(4, bc, 2), 256, 0, stream>>>(
        attnH, attnL, PTh + off, PTl + off, ATh + off, ATl + off,
        A + off, P + off, out1 + off, out2 + off, Bc);
  }
}

// Round 4
// 278.876 us; speedup vs baseline: 2.2814x; 1.0519x over previous
//
#include <hip/hip_runtime.h>

// Problem constants: B=32, S=128, H=512, K=8
#define BB 32
#define SS 128
#define HH 512
#define KC 8
#define NN 4096  // KC*HH

typedef __attribute__((ext_vector_type(8))) short bf16x8;
typedef __attribute__((ext_vector_type(4))) float f32x4;

__device__ __forceinline__ unsigned short f2bf(float f) {
  unsigned int u = __float_as_uint(f);
  u += 0x7fffu + ((u >> 16) & 1u);   // round-to-nearest-even
  return (unsigned short)(u >> 16);
}
__device__ __forceinline__ float bf2f(unsigned short h) {
  return __uint_as_float(((unsigned int)h) << 16);
}
__device__ __forceinline__ float tanh_fast(float x) {
  float e = __expf(2.0f * x);
  return 1.0f - 2.0f / (e + 1.0f);
}
__device__ __forceinline__ void async16(const void* g, void* lds) {
  __builtin_amdgcn_global_load_lds(
      (const __attribute__((address_space(1))) unsigned int*)g,
      (__attribute__((address_space(3))) unsigned int*)lds, 16, 0, 0);
}

// ---- conversion kernels (merged via blockIdx.z) ---------------------------
__global__ __launch_bounds__(256) void convert_split2(
    const float* __restrict__ X0, const float* __restrict__ X1,
    unsigned short* __restrict__ h0, unsigned short* __restrict__ l0,
    unsigned short* __restrict__ h1, unsigned short* __restrict__ l1, int n) {
  const float* x = blockIdx.z ? X1 : X0;
  unsigned short* hi = blockIdx.z ? h1 : h0;
  unsigned short* lo = blockIdx.z ? l1 : l0;
  int i = (blockIdx.x * 256 + threadIdx.x) * 4;
  if (i >= n) return;
  float4 f = *(const float4*)&x[i];
  ushort4 h, l;
  h.x = f2bf(f.x); l.x = f2bf(f.x - bf2f(h.x));
  h.y = f2bf(f.y); l.y = f2bf(f.y - bf2f(h.y));
  h.z = f2bf(f.z); l.z = f2bf(f.z - bf2f(h.z));
  h.w = f2bf(f.w); l.w = f2bf(f.w - bf2f(h.w));
  *(ushort4*)&hi[i] = h;
  *(ushort4*)&lo[i] = l;
}

// G [512, 4096] fp32 -> G^T [4096, 512] (hi, lo) bf16; z selects G1/G2.
__global__ __launch_bounds__(256) void convert_transpose_g(
    const float* __restrict__ Ga, const float* __restrict__ Gb,
    unsigned short* __restrict__ ha, unsigned short* __restrict__ la,
    unsigned short* __restrict__ hb, unsigned short* __restrict__ lb) {
  const float* G = blockIdx.z ? Gb : Ga;
  unsigned short* hiT = blockIdx.z ? hb : ha;
  unsigned short* loT = blockIdx.z ? lb : la;
  __shared__ float t[32][33];
  const int bx = blockIdx.x * 32;  // n
  const int by = blockIdx.y * 32;  // k
  const int tx = threadIdx.x & 31, ty = threadIdx.x >> 5;
#pragma unroll
  for (int r = 0; r < 4; ++r)
    t[ty + r * 8][tx] = G[(size_t)(by + ty + r * 8) * NN + bx + tx];
  __syncthreads();
#pragma unroll
  for (int r = 0; r < 4; ++r) {
    float f = t[tx][ty + r * 8];
    size_t o = (size_t)(bx + ty + r * 8) * HH + by + tx;
    unsigned short h = f2bf(f);
    hiT[o] = h;
    loT[o] = f2bf(f - bf2f(h));
  }
}

// X [B,S,H] fp32 -> X^T [B,H,S] (hi, lo) bf16; z selects A/P. y encodes (b, s0).
__global__ __launch_bounds__(256) void convert_transpose_b2(
    const float* __restrict__ Xa, const float* __restrict__ Xb,
    unsigned short* __restrict__ ha, unsigned short* __restrict__ la,
    unsigned short* __restrict__ hb, unsigned short* __restrict__ lb) {
  const float* X = blockIdx.z ? Xb : Xa;
  unsigned short* hiT = blockIdx.z ? hb : ha;
  unsigned short* loT = blockIdx.z ? lb : la;
  __shared__ float t[32][33];
  const int h0 = blockIdx.x * 32;
  const int s0 = (blockIdx.y & 3) * 32;
  const size_t b = blockIdx.y >> 2;
  const int tx = threadIdx.x & 31, ty = threadIdx.x >> 5;
#pragma unroll
  for (int r = 0; r < 4; ++r)
    t[ty + r * 8][tx] = X[b * (SS * HH) + (size_t)(s0 + ty + r * 8) * HH + h0 + tx];
  __syncthreads();
#pragma unroll
  for (int r = 0; r < 4; ++r) {
    float f = t[tx][ty + r * 8];
    size_t o = b * (SS * HH) + (size_t)(h0 + ty + r * 8) * SS + s0 + tx;
    unsigned short h = f2bf(f);
    hiT[o] = h;
    loT[o] = f2bf(f - bf2f(h));
  }
}

// ---- shared 128x128xK split-bf16 MFMA core --------------------------------
// sm layout (bytes): [0,8192) Ahi, [8192,16384) Alo, [16384,24576) Bhi,
// [24576,32768) Blo; each tile [128 rows][32 k] ushort.
template <int SA, int SB, int KIT>
__device__ __forceinline__ void mm128_core(
    const unsigned short* __restrict__ Ah, const unsigned short* __restrict__ Al,
    const unsigned short* __restrict__ Bh, const unsigned short* __restrict__ Bl,
    unsigned short* sm, f32x4 acc[4][4]) {
  const int tid = threadIdx.x;
  const int w = tid >> 6, L = tid & 63;
  const int wm = w >> 1, wn = w & 1;
  char* smb = (char*)sm;
  const int srow = w * 32 + (L >> 2);
  const int scol = (L & 3) * 8;
  const unsigned short* pAh = Ah + (size_t)srow * SA + scol;
  const unsigned short* pAl = Al + (size_t)srow * SA + scol;
  const unsigned short* pBh = Bh + (size_t)srow * SB + scol;
  const unsigned short* pBl = Bl + (size_t)srow * SB + scol;
  const unsigned lbase = (unsigned)w * 2048;
  const int ar = (wm * 64 + (L & 15)) * 32 + (L >> 4) * 8;
  const int br = (wn * 64 + (L & 15)) * 32 + (L >> 4) * 8;

  for (int kt = 0; kt < KIT; ++kt) {
    const int k0 = kt * 32;
    async16(pAh + k0, smb + lbase);
    async16(pAh + k0 + 16 * SA, smb + lbase + 1024);
    async16(pAl + k0, smb + 8192 + lbase);
    async16(pAl + k0 + 16 * SA, smb + 8192 + lbase + 1024);
    async16(pBh + k0, smb + 16384 + lbase);
    async16(pBh + k0 + 16 * SB, smb + 16384 + lbase + 1024);
    async16(pBl + k0, smb + 24576 + lbase);
    async16(pBl + k0 + 16 * SB, smb + 24576 + lbase + 1024);
    __syncthreads();
    bf16x8 ah[4], al[4], bh[4], bl[4];
#pragma unroll
    for (int i = 0; i < 4; ++i) {
      ah[i] = *(const bf16x8*)&sm[ar + i * 512];
      al[i] = *(const bf16x8*)&sm[4096 + ar + i * 512];
      bh[i] = *(const bf16x8*)&sm[8192 + br + i * 512];
      bl[i] = *(const bf16x8*)&sm[12288 + br + i * 512];
    }
#pragma unroll
    for (int i = 0; i < 4; ++i)
#pragma unroll
      for (int j = 0; j < 4; ++j) {
        acc[i][j] = __builtin_amdgcn_mfma_f32_16x16x32_bf16(ah[i], bh[j], acc[i][j], 0, 0, 0);
        acc[i][j] = __builtin_amdgcn_mfma_f32_16x16x32_bf16(ah[i], bl[j], acc[i][j], 0, 0, 0);
        acc[i][j] = __builtin_amdgcn_mfma_f32_16x16x32_bf16(al[i], bh[j], acc[i][j], 0, 0, 0);
      }
    __syncthreads();
  }
}

// ---- proj GEMM (both branches): C[M,4096] = A[M,512] @ G[512,4096] --------
__global__ __launch_bounds__(256) void gemm_split(
    const unsigned short* __restrict__ Ahi, const unsigned short* __restrict__ Alo,
    const unsigned short* __restrict__ G1h, const unsigned short* __restrict__ G1l,
    const unsigned short* __restrict__ G2h, const unsigned short* __restrict__ G2l,
    unsigned short* __restrict__ C1h, unsigned short* __restrict__ C1l,
    unsigned short* __restrict__ C2h, unsigned short* __restrict__ C2l) {
  __shared__ unsigned short sm[16384];
  const int bn = blockIdx.x * 128, bm = blockIdx.y * 128, brx = blockIdx.z;
  const unsigned short* Bh = (brx ? G2h : G1h) + (size_t)bn * HH;
  const unsigned short* Bl = (brx ? G2l : G1l) + (size_t)bn * HH;
  unsigned short* Ch = brx ? C2h : C1h;
  unsigned short* Cl = brx ? C2l : C1l;
  f32x4 acc[4][4];
#pragma unroll
  for (int i = 0; i < 4; ++i)
#pragma unroll
    for (int j = 0; j < 4; ++j) acc[i][j] = (f32x4)(0.0f);
  mm128_core<HH, HH, 16>(Ahi + (size_t)bm * HH, Alo + (size_t)bm * HH, Bh, Bl, sm, acc);
  const int tid = threadIdx.x, L = tid & 63, w = tid >> 6;
  const int wm = w >> 1, wn = w & 1;
  const int q = L >> 4, c = L & 15;
#pragma unroll
  for (int i = 0; i < 4; ++i)
#pragma unroll
    for (int j = 0; j < 4; ++j) {
      const int row = bm + wm * 64 + i * 16 + q * 4;
      const int col = bn + wn * 64 + j * 16 + c;
#pragma unroll
      for (int r = 0; r < 4; ++r) {
        float f = acc[i][j][r];
        unsigned short h = f2bf(f);
        size_t o = (size_t)(row + r) * NN + col;
        Ch[o] = h;
        Cl[o] = f2bf(f - bf2f(h));
      }
    }
}

// ---- fused: score GEMM + tanh/k-combine + softmax + PV + residual ---------
// Block (rt, b, br): 16 s-rows (128 proj rows = 16s x 8k), all 128 t.
// After softmax, attn (bf16 hi/lo) stays in LDS; PV = attn[16x128] @ V[128x512]
// via split-MFMA with V^T staged in the core's B regions.
__global__ __launch_bounds__(256) void attn_fused2(
    const unsigned short* __restrict__ P1h, const unsigned short* __restrict__ P1l,
    const unsigned short* __restrict__ P2h, const unsigned short* __restrict__ P2l,
    const unsigned short* __restrict__ R1h, const unsigned short* __restrict__ R1l,
    const unsigned short* __restrict__ R2h, const unsigned short* __restrict__ R2l,
    const unsigned short* __restrict__ PTh, const unsigned short* __restrict__ PTl,
    const unsigned short* __restrict__ ATh, const unsigned short* __restrict__ ATl,
    const float* __restrict__ Abase, const float* __restrict__ Pbase,
    const float* __restrict__ v1, const float* __restrict__ v2,
    float* __restrict__ out1, float* __restrict__ out2) {
  __shared__ char smem[32768];
  unsigned short* sm = (unsigned short*)smem;
  const int b = blockIdx.y, rt = blockIdx.x, brx = blockIdx.z;
  const unsigned short* Pjh = (brx ? P2h : P1h) + ((size_t)b * 1024 + (size_t)rt * 128) * HH;
  const unsigned short* Pjl = (brx ? P2l : P1l) + ((size_t)b * 1024 + (size_t)rt * 128) * HH;
  const unsigned short* Rh = (brx ? R2h : R1h) + (size_t)b * SS * HH;
  const unsigned short* Rl = (brx ? R2l : R1l) + (size_t)b * SS * HH;
  const float* v = brx ? v2 : v1;
  f32x4 acc[4][4];
#pragma unroll
  for (int i = 0; i < 4; ++i)
#pragma unroll
    for (int j = 0; j < 4; ++j) acc[i][j] = (f32x4)(0.0f);
  mm128_core<HH, HH, 16>(Pjh, Pjl, Rh, Rl, sm, acc);

  // ---- tanh + k-combine -> scoresS (aliases staging region, now free) ----
  float (*scoresS)[132] = (float(*)[132])smem;  // [16][132], 8448 B
  const int tid = threadIdx.x, L = tid & 63, w = tid >> 6;
  const int wm = w >> 1, wn = w & 1;
  const int q = L >> 4, c = L & 15;
  float vk[KC];
#pragma unroll
  for (int k = 0; k < KC; ++k) vk[k] = v[k];
  // C frag row = local (s,k): k = (q&1)*4 + r, s_loc = wm*8 + i*2 + (q>>1)
#pragma unroll
  for (int i = 0; i < 4; ++i)
#pragma unroll
    for (int j = 0; j < 4; ++j) {
      float part = 0.0f;
#pragma unroll
      for (int r = 0; r < 4; ++r)
        part = fmaf(vk[(q & 1) * 4 + r], tanh_fast(acc[i][j][r]), part);
      part += __shfl_xor(part, 16);  // combine k halves
      if ((q & 1) == 0)
        scoresS[wm * 8 + i * 2 + (q >> 1)][wn * 64 + j * 16 + c] = part;
    }
  __syncthreads();

  // ---- softmax over t (128), 16 threads per s-row ----
  const int tx = tid & 15, ty = tid >> 4;
  float sc[8];
#pragma unroll
  for (int j = 0; j < 8; ++j) sc[j] = scoresS[ty][tx * 8 + j];
  float mx = sc[0];
#pragma unroll
  for (int j = 1; j < 8; ++j) mx = fmaxf(mx, sc[j]);
#pragma unroll
  for (int off = 1; off < 16; off <<= 1) mx = fmaxf(mx, __shfl_xor(mx, off, 16));
  float p[8], ssum = 0.0f;
#pragma unroll
  for (int j = 0; j < 8; ++j) { p[j] = __expf(sc[j] - mx); ssum += p[j]; }
#pragma unroll
  for (int off = 1; off < 16; off <<= 1) ssum += __shfl_xor(ssum, off, 16);
  float inv = 1.0f / ssum;
  __syncthreads();  // all scoresS reads done before aliasing with attn arrays

  // ---- attn weights bf16 hi/lo into LDS (row stride 136 breaks conflicts) --
  unsigned short* attnHi = (unsigned short*)smem;            // [16][136]
  unsigned short* attnLo = (unsigned short*)(smem + 4352);   // [16][136]
  {
    unsigned short hh[8], ll[8];
#pragma unroll
    for (int j = 0; j < 8; ++j) {
      float wgt = p[j] * inv;
      hh[j] = f2bf(wgt);
      ll[j] = f2bf(wgt - bf2f(hh[j]));
    }
    *(ushort4*)&attnHi[ty * 136 + tx * 8]     = make_ushort4(hh[0], hh[1], hh[2], hh[3]);
    *(ushort4*)&attnHi[ty * 136 + tx * 8 + 4] = make_ushort4(hh[4], hh[5], hh[6], hh[7]);
    *(ushort4*)&attnLo[ty * 136 + tx * 8]     = make_ushort4(ll[0], ll[1], ll[2], ll[3]);
    *(ushort4*)&attnLo[ty * 136 + tx * 8 + 4] = make_ushort4(ll[4], ll[5], ll[6], ll[7]);
  }
  __syncthreads();

  // ---- PV: out[s, 0:512] = base + attn[16x128] @ V[128x512] ----
  // V^T [512 h][128 t] split; stage [128 h x 32 t] tiles in the core B regions.
  const unsigned short* Vh = (brx ? ATh : PTh) + (size_t)b * HH * SS;
  const unsigned short* Vl = (brx ? ATl : PTl) + (size_t)b * HH * SS;
  const float* base = (brx ? Pbase : Abase) + (size_t)b * SS * HH;
  float* outp = (brx ? out2 : out1) + (size_t)b * SS * HH;
  char* smb = smem;
  const int srow = w * 32 + (L >> 2);
  const int scol = (L & 3) * 8;
  const unsigned lbase = (unsigned)w * 2048;

  for (int nc = 0; nc < 4; ++nc) {
    f32x4 pacc[2];
    pacc[0] = (f32x4)(0.0f);
    pacc[1] = (f32x4)(0.0f);
    const unsigned short* pVh = Vh + (size_t)(nc * 128 + srow) * SS + scol;
    const unsigned short* pVl = Vl + (size_t)(nc * 128 + srow) * SS + scol;
#pragma unroll
    for (int kt = 0; kt < 4; ++kt) {
      const int k0 = kt * 32;
      async16(pVh + k0, smb + 16384 + lbase);
      async16(pVh + k0 + 16 * SS, smb + 16384 + lbase + 1024);
      async16(pVl + k0, smb + 24576 + lbase);
      async16(pVl + k0 + 16 * SS, smb + 24576 + lbase + 1024);
      __syncthreads();
      bf16x8 pah = *(const bf16x8*)&attnHi[(L & 15) * 136 + k0 + (L >> 4) * 8];
      bf16x8 pal = *(const bf16x8*)&attnLo[(L & 15) * 136 + k0 + (L >> 4) * 8];
#pragma unroll
      for (int j = 0; j < 2; ++j) {
        const int brow = (w * 32 + j * 16 + (L & 15)) * 32 + (L >> 4) * 8;
        bf16x8 pbh = *(const bf16x8*)&sm[8192 + brow];
        bf16x8 pbl = *(const bf16x8*)&sm[12288 + brow];
        pacc[j] = __builtin_amdgcn_mfma_f32_16x16x32_bf16(pah, pbh, pacc[j], 0, 0, 0);
        pacc[j] = __builtin_amdgcn_mfma_f32_16x16x32_bf16(pah, pbl, pacc[j], 0, 0, 0);
        pacc[j] = __builtin_amdgcn_mfma_f32_16x16x32_bf16(pal, pbh, pacc[j], 0, 0, 0);
      }
      __syncthreads();
    }
    // epilogue: C rows s = q*4+r, cols h = nc*128 + w*32 + j*16 + c
#pragma unroll
    for (int j = 0; j < 2; ++j) {
      const int hcol = nc * 128 + w * 32 + j * 16 + c;
#pragma unroll
      for (int r = 0; r < 4; ++r) {
        size_t o = (size_t)(rt * 16 + q * 4 + r) * HH + hcol;
        outp[o] = base[o] + pacc[j][r];
      }
    }
  }
}

extern "C" void kernel_launch(void* const* d_in, const int* in_sizes, int n_in,
                              void* d_out, int out_size, void* d_ws, size_t ws_size,
                              hipStream_t stream) {
  const float* A  = (const float*)d_in[0];
  const float* P  = (const float*)d_in[1];
  const float* G1 = (const float*)d_in[2];
  const float* G2 = (const float*)d_in[3];
  const float* v1 = (const float*)d_in[4];
  const float* v2 = (const float*)d_in[5];
  float* out1 = (float*)d_out;
  float* out2 = out1 + (size_t)BB * SS * HH;

  const size_t NA = (size_t)BB * SS * HH;  // 2M
  const size_t NG = (size_t)HH * KC * HH;  // 2M
  unsigned short* Ahi = (unsigned short*)d_ws;
  unsigned short* Alo = Ahi + NA;
  unsigned short* Phi = Alo + NA;
  unsigned short* Plo = Phi + NA;
  unsigned short* G1h = Plo + NA;
  unsigned short* G1l = G1h + NG;
  unsigned short* G2h = G1l + NG;
  unsigned short* G2l = G2h + NG;
  unsigned short* ATh = G2l + NG;
  unsigned short* ATl = ATh + NA;
  unsigned short* PTh = ATl + NA;
  unsigned short* PTl = PTh + NA;
  unsigned short* dyn = PTl + NA;

  const size_t fixedBytes = (8 * NA + 4 * NG) * sizeof(unsigned short);  // 48 MB
  const size_t projPerB = (size_t)SS * NN;  // ushorts per batch per buffer
  const size_t perB = 4 * projPerB * sizeof(unsigned short);  // 4 MB/batch
  size_t rem = ws_size > fixedBytes ? ws_size - fixedBytes : 0;
  int Bc = (int)(rem / perB);
  if (Bc < 1) Bc = 1;
  if (Bc > BB) Bc = BB;
  unsigned short* prjH1 = dyn;
  unsigned short* prjL1 = prjH1 + (size_t)Bc * projPerB;
  unsigned short* prjH2 = prjL1 + (size_t)Bc * projPerB;
  unsigned short* prjL2 = prjH2 + (size_t)Bc * projPerB;

  convert_split2<<<dim3((unsigned)(NA / 1024), 1, 2), 256, 0, stream>>>(
      A, P, Ahi, Alo, Phi, Plo, (int)NA);
  convert_transpose_g<<<dim3(NN / 32, HH / 32, 2), 256, 0, stream>>>(
      G1, G2, G1h, G1l, G2h, G2l);
  convert_transpose_b2<<<dim3(HH / 32, (SS / 32) * BB, 2), 256, 0, stream>>>(
      A, P, ATh, ATl, PTh, PTl);

  for (int b0 = 0; b0 < BB; b0 += Bc) {
    int bc = (Bc < BB - b0) ? Bc : (BB - b0);
    size_t off = (size_t)b0 * SS * HH;  // element offset (both layouts)
    gemm_split<<<dim3(NN / 128, bc, 2), 256, 0, stream>>>(
        Ahi + off, Alo + off, G1h, G1l, G2h, G2l,
        prjH1, prjL1, prjH2, prjL2);
    attn_fused2<<<dim3(8, bc, 2), 256, 0, stream>>>(
        prjH1, prjL1, prjH2, prjL2,
        Phi + off, Plo + off, Ahi + off, Alo + off,
        PTh + off, PTl + off, ATh + off, ATl + off,
        A + off, P + off, v1, v2, out1 + off, out2 + off);
  }
}

// Round 5
// 265.999 us; speedup vs baseline: 2.3918x; 1.0484x over previous
//
#include <hip/hip_runtime.h>

// Problem constants: B=32, S=128, H=512, K=8
#define BB 32
#define SS 128
#define HH 512
#define KC 8
#define NN 4096  // KC*HH

typedef __attribute__((ext_vector_type(8))) short bf16x8;
typedef __attribute__((ext_vector_type(4))) float f32x4;

__device__ __forceinline__ unsigned short f2bf(float f) {
  unsigned int u = __float_as_uint(f);
  u += 0x7fffu + ((u >> 16) & 1u);   // round-to-nearest-even
  return (unsigned short)(u >> 16);
}
__device__ __forceinline__ float bf2f(unsigned short h) {
  return __uint_as_float(((unsigned int)h) << 16);
}
__device__ __forceinline__ float tanh_fast(float x) {
  float e = __expf(2.0f * x);
  return 1.0f - 2.0f / (e + 1.0f);
}
__device__ __forceinline__ void async16(const void* g, void* lds) {
  __builtin_amdgcn_global_load_lds(
      (const __attribute__((address_space(1))) unsigned int*)g,
      (__attribute__((address_space(3))) unsigned int*)lds, 16, 0, 0);
}

// ---- conversion kernels ---------------------------------------------------
__global__ __launch_bounds__(256) void convert_split2(
    const float* __restrict__ X0, const float* __restrict__ X1,
    unsigned short* __restrict__ h0, unsigned short* __restrict__ l0,
    unsigned short* __restrict__ h1, unsigned short* __restrict__ l1, int n) {
  const float* x = blockIdx.z ? X1 : X0;
  unsigned short* hi = blockIdx.z ? h1 : h0;
  unsigned short* lo = blockIdx.z ? l1 : l0;
  int i = (blockIdx.x * 256 + threadIdx.x) * 4;
  if (i >= n) return;
  float4 f = *(const float4*)&x[i];
  ushort4 h, l;
  h.x = f2bf(f.x); l.x = f2bf(f.x - bf2f(h.x));
  h.y = f2bf(f.y); l.y = f2bf(f.y - bf2f(h.y));
  h.z = f2bf(f.z); l.z = f2bf(f.z - bf2f(h.z));
  h.w = f2bf(f.w); l.w = f2bf(f.w - bf2f(h.w));
  *(ushort4*)&hi[i] = h;
  *(ushort4*)&lo[i] = l;
}

// G [512, 4096] fp32 -> G^T [4096, 512] (hi, lo) bf16; z selects G1/G2.
__global__ __launch_bounds__(256) void convert_transpose_g(
    const float* __restrict__ Ga, const float* __restrict__ Gb,
    unsigned short* __restrict__ ha, unsigned short* __restrict__ la,
    unsigned short* __restrict__ hb, unsigned short* __restrict__ lb) {
  const float* G = blockIdx.z ? Gb : Ga;
  unsigned short* hiT = blockIdx.z ? hb : ha;
  unsigned short* loT = blockIdx.z ? lb : la;
  __shared__ float t[32][33];
  const int bx = blockIdx.x * 32;  // n
  const int by = blockIdx.y * 32;  // k
  const int tx = threadIdx.x & 31, ty = threadIdx.x >> 5;
#pragma unroll
  for (int r = 0; r < 4; ++r)
    t[ty + r * 8][tx] = G[(size_t)(by + ty + r * 8) * NN + bx + tx];
  __syncthreads();
#pragma unroll
  for (int r = 0; r < 4; ++r) {
    float f = t[tx][ty + r * 8];
    size_t o = (size_t)(bx + ty + r * 8) * HH + by + tx;
    unsigned short h = f2bf(f);
    hiT[o] = h;
    loT[o] = f2bf(f - bf2f(h));
  }
}

// X [B,S,H] fp32 -> X^T [B,H,S] hi-only bf16 (PV V-operand); z selects A/P.
__global__ __launch_bounds__(256) void convert_transpose_bh(
    const float* __restrict__ Xa, const float* __restrict__ Xb,
    unsigned short* __restrict__ ha, unsigned short* __restrict__ hb) {
  const float* X = blockIdx.z ? Xb : Xa;
  unsigned short* hiT = blockIdx.z ? hb : ha;
  __shared__ float t[32][33];
  const int h0 = blockIdx.x * 32;
  const int s0 = (blockIdx.y & 3) * 32;
  const size_t b = blockIdx.y >> 2;
  const int tx = threadIdx.x & 31, ty = threadIdx.x >> 5;
#pragma unroll
  for (int r = 0; r < 4; ++r)
    t[ty + r * 8][tx] = X[b * (SS * HH) + (size_t)(s0 + ty + r * 8) * HH + h0 + tx];
  __syncthreads();
#pragma unroll
  for (int r = 0; r < 4; ++r) {
    float f = t[tx][ty + r * 8];
    size_t o = b * (SS * HH) + (size_t)(h0 + ty + r * 8) * SS + s0 + tx;
    hiT[o] = f2bf(f);
  }
}

// ---- 128x128x512 split-bf16 MFMA core (gemm_split only) -------------------
__device__ __forceinline__ void mm128_core(
    const unsigned short* __restrict__ Ah, const unsigned short* __restrict__ Al,
    const unsigned short* __restrict__ Bh, const unsigned short* __restrict__ Bl,
    unsigned short* sm, f32x4 acc[4][4]) {
  const int tid = threadIdx.x;
  const int w = tid >> 6, L = tid & 63;
  const int wm = w >> 1, wn = w & 1;
  char* smb = (char*)sm;
  const int srow = w * 32 + (L >> 2);
  const int scol = (L & 3) * 8;
  const unsigned short* pAh = Ah + (size_t)srow * HH + scol;
  const unsigned short* pAl = Al + (size_t)srow * HH + scol;
  const unsigned short* pBh = Bh + (size_t)srow * HH + scol;
  const unsigned short* pBl = Bl + (size_t)srow * HH + scol;
  const unsigned lbase = (unsigned)w * 2048;
  const int ar = (wm * 64 + (L & 15)) * 32 + (L >> 4) * 8;
  const int br = (wn * 64 + (L & 15)) * 32 + (L >> 4) * 8;

  for (int kt = 0; kt < 16; ++kt) {
    const int k0 = kt * 32;
    async16(pAh + k0, smb + lbase);
    async16(pAh + k0 + 16 * HH, smb + lbase + 1024);
    async16(pAl + k0, smb + 8192 + lbase);
    async16(pAl + k0 + 16 * HH, smb + 8192 + lbase + 1024);
    async16(pBh + k0, smb + 16384 + lbase);
    async16(pBh + k0 + 16 * HH, smb + 16384 + lbase + 1024);
    async16(pBl + k0, smb + 24576 + lbase);
    async16(pBl + k0 + 16 * HH, smb + 24576 + lbase + 1024);
    __syncthreads();
    bf16x8 ah[4], al[4], bh[4], bl[4];
#pragma unroll
    for (int i = 0; i < 4; ++i) {
      ah[i] = *(const bf16x8*)&sm[ar + i * 512];
      al[i] = *(const bf16x8*)&sm[4096 + ar + i * 512];
      bh[i] = *(const bf16x8*)&sm[8192 + br + i * 512];
      bl[i] = *(const bf16x8*)&sm[12288 + br + i * 512];
    }
#pragma unroll
    for (int i = 0; i < 4; ++i)
#pragma unroll
      for (int j = 0; j < 4; ++j) {
        acc[i][j] = __builtin_amdgcn_mfma_f32_16x16x32_bf16(ah[i], bh[j], acc[i][j], 0, 0, 0);
        acc[i][j] = __builtin_amdgcn_mfma_f32_16x16x32_bf16(ah[i], bl[j], acc[i][j], 0, 0, 0);
        acc[i][j] = __builtin_amdgcn_mfma_f32_16x16x32_bf16(al[i], bh[j], acc[i][j], 0, 0, 0);
      }
    __syncthreads();
  }
}

// ---- proj GEMM (both branches): C[M,4096] = A[M,512] @ G[512,4096] --------
__global__ __launch_bounds__(256) void gemm_split(
    const unsigned short* __restrict__ Ahi, const unsigned short* __restrict__ Alo,
    const unsigned short* __restrict__ G1h, const unsigned short* __restrict__ G1l,
    const unsigned short* __restrict__ G2h, const unsigned short* __restrict__ G2l,
    unsigned short* __restrict__ C1h, unsigned short* __restrict__ C1l,
    unsigned short* __restrict__ C2h, unsigned short* __restrict__ C2l) {
  __shared__ unsigned short sm[16384];
  const int bn = blockIdx.x * 128, bm = blockIdx.y * 128, brx = blockIdx.z;
  const unsigned short* Bh = (brx ? G2h : G1h) + (size_t)bn * HH;
  const unsigned short* Bl = (brx ? G2l : G1l) + (size_t)bn * HH;
  unsigned short* Ch = brx ? C2h : C1h;
  unsigned short* Cl = brx ? C2l : C1l;
  f32x4 acc[4][4];
#pragma unroll
  for (int i = 0; i < 4; ++i)
#pragma unroll
    for (int j = 0; j < 4; ++j) acc[i][j] = (f32x4)(0.0f);
  mm128_core(Ahi + (size_t)bm * HH, Alo + (size_t)bm * HH, Bh, Bl, sm, acc);
  const int tid = threadIdx.x, L = tid & 63, w = tid >> 6;
  const int wm = w >> 1, wn = w & 1;
  const int q = L >> 4, c = L & 15;
#pragma unroll
  for (int i = 0; i < 4; ++i)
#pragma unroll
    for (int j = 0; j < 4; ++j) {
      const int row = bm + wm * 64 + i * 16 + q * 4;
      const int col = bn + wn * 64 + j * 16 + c;
#pragma unroll
      for (int r = 0; r < 4; ++r) {
        float f = acc[i][j][r];
        unsigned short h = f2bf(f);
        size_t o = (size_t)(row + r) * NN + col;
        Ch[o] = h;
        Cl[o] = f2bf(f - bf2f(h));
      }
    }
}

// ---- fused attn: 1024 blocks (16 rt, B, 2 br), M=64 (8 s x 8 k) ----------
// Score: raw[64 x 128t] = proj_rows[64 x 512] . R[128 x 512]^T (split, 3-MFMA).
// Wave w computes all 64 rows x t-cols [w*32, w*32+32) -> acc[4][2].
// Then tanh + v-combine + softmax (8 s-rows), attn bf16-hi in LDS,
// PV hi-only: out[8 x 512] = base + attn[8x128] @ V[128x512].
__global__ __launch_bounds__(256, 4) void attn_fused3(
    const unsigned short* __restrict__ P1h, const unsigned short* __restrict__ P1l,
    const unsigned short* __restrict__ P2h, const unsigned short* __restrict__ P2l,
    const unsigned short* __restrict__ R1h, const unsigned short* __restrict__ R1l,
    const unsigned short* __restrict__ R2h, const unsigned short* __restrict__ R2l,
    const unsigned short* __restrict__ PTh, const unsigned short* __restrict__ ATh,
    const float* __restrict__ Abase, const float* __restrict__ Pbase,
    const float* __restrict__ v1, const float* __restrict__ v2,
    float* __restrict__ out1, float* __restrict__ out2) {
  // [0,4352): attnHi [16][136] ushort (rows 8..15 never written -> garbage,
  //           but their C rows are never stored). [4608, 37376): staging.
  __shared__ char smem[37376];
  const int b = blockIdx.y, rt = blockIdx.x, brx = blockIdx.z;
  const int tid = threadIdx.x, w = tid >> 6, L = tid & 63;

  const unsigned short* Ah = (brx ? P2h : P1h) + ((size_t)b * 1024 + (size_t)rt * 64) * HH;
  const unsigned short* Al = (brx ? P2l : P1l) + ((size_t)b * 1024 + (size_t)rt * 64) * HH;
  const unsigned short* Bh = (brx ? R2h : R1h) + (size_t)b * SS * HH;
  const unsigned short* Bl = (brx ? R2l : R1l) + (size_t)b * SS * HH;
  const float* v = brx ? v2 : v1;

  unsigned short* cs = (unsigned short*)(smem + 4608);
  char* csb = smem + 4608;
  // ushort offsets within cs: Ahi [0,2048) Alo [2048,4096) Bhi [4096,8192) Blo [8192,12288)

  f32x4 acc[4][2];
#pragma unroll
  for (int i = 0; i < 4; ++i) { acc[i][0] = (f32x4)(0.0f); acc[i][1] = (f32x4)(0.0f); }

  const int scol = (L & 3) * 8;
  const unsigned short* pAh = Ah + (size_t)(w * 16 + (L >> 2)) * HH + scol;
  const unsigned short* pAl = Al + (size_t)(w * 16 + (L >> 2)) * HH + scol;
  const unsigned short* pBh = Bh + (size_t)(w * 32 + (L >> 2)) * HH + scol;
  const unsigned short* pBl = Bl + (size_t)(w * 32 + (L >> 2)) * HH + scol;
  const unsigned laA = (unsigned)w * 1024;
  const unsigned laB = (unsigned)w * 2048;
  const int afr = (L & 15) * 32 + (L >> 4) * 8;               // + i*512
  const int bfr = (w * 32 + (L & 15)) * 32 + (L >> 4) * 8;    // + j*512

  for (int kt = 0; kt < 16; ++kt) {
    const int k0 = kt * 32;
    async16(pAh + k0, csb + laA);
    async16(pAl + k0, csb + 4096 + laA);
    async16(pBh + k0, csb + 8192 + laB);
    async16(pBh + k0 + 16 * HH, csb + 8192 + laB + 1024);
    async16(pBl + k0, csb + 16384 + laB);
    async16(pBl + k0 + 16 * HH, csb + 16384 + laB + 1024);
    __syncthreads();
    bf16x8 ah[4], al[4], bhf[2], blf[2];
#pragma unroll
    for (int i = 0; i < 4; ++i) {
      ah[i] = *(const bf16x8*)&cs[afr + i * 512];
      al[i] = *(const bf16x8*)&cs[2048 + afr + i * 512];
    }
#pragma unroll
    for (int j = 0; j < 2; ++j) {
      bhf[j] = *(const bf16x8*)&cs[4096 + bfr + j * 512];
      blf[j] = *(const bf16x8*)&cs[8192 + bfr + j * 512];
    }
#pragma unroll
    for (int i = 0; i < 4; ++i)
#pragma unroll
      for (int j = 0; j < 2; ++j) {
        acc[i][j] = __builtin_amdgcn_mfma_f32_16x16x32_bf16(ah[i], bhf[j], acc[i][j], 0, 0, 0);
        acc[i][j] = __builtin_amdgcn_mfma_f32_16x16x32_bf16(ah[i], blf[j], acc[i][j], 0, 0, 0);
        acc[i][j] = __builtin_amdgcn_mfma_f32_16x16x32_bf16(al[i], bhf[j], acc[i][j], 0, 0, 0);
      }
    __syncthreads();
  }

  // ---- tanh + k-combine -> scoresS[8][132] (aliases staging region) ----
  float (*scoresS)[132] = (float(*)[132])(smem + 4608);
  unsigned short* attnHi = (unsigned short*)smem;  // [16][136]
  const int q = L >> 4, c = L & 15;
  float vk[KC];
#pragma unroll
  for (int k = 0; k < KC; ++k) vk[k] = v[k];
  // C row = i*16 + q*4 + r = s_loc*8 + k with k=(q&1)*4+r, s_loc=i*2+(q>>1)
#pragma unroll
  for (int i = 0; i < 4; ++i)
#pragma unroll
    for (int j = 0; j < 2; ++j) {
      float part = 0.0f;
#pragma unroll
      for (int r = 0; r < 4; ++r)
        part = fmaf(vk[(q & 1) * 4 + r], tanh_fast(acc[i][j][r]), part);
      part += __shfl_xor(part, 16);  // combine k halves (q ^ 1)
      if ((q & 1) == 0)
        scoresS[i * 2 + (q >> 1)][w * 32 + j * 16 + c] = part;
    }
  __syncthreads();

  // ---- softmax: 8 s-rows x 128 t, 32 threads/row ----
  const int ty = tid >> 5, tx = tid & 31;
  float sc[4];
#pragma unroll
  for (int j = 0; j < 4; ++j) sc[j] = scoresS[ty][tx * 4 + j];
  float mx = fmaxf(fmaxf(sc[0], sc[1]), fmaxf(sc[2], sc[3]));
#pragma unroll
  for (int off = 1; off < 32; off <<= 1) mx = fmaxf(mx, __shfl_xor(mx, off, 32));
  float p[4], ssum = 0.0f;
#pragma unroll
  for (int j = 0; j < 4; ++j) { p[j] = __expf(sc[j] - mx); ssum += p[j]; }
#pragma unroll
  for (int off = 1; off < 32; off <<= 1) ssum += __shfl_xor(ssum, off, 32);
  float inv = 1.0f / ssum;
  ushort4 hq;
  hq.x = f2bf(p[0] * inv); hq.y = f2bf(p[1] * inv);
  hq.z = f2bf(p[2] * inv); hq.w = f2bf(p[3] * inv);
  *(ushort4*)&attnHi[ty * 136 + tx * 4] = hq;
  __syncthreads();  // attn written; staging region free for V tiles

  // ---- PV hi-only: out[8 x 512] = base + attn[8x128] @ V[128x512] ----
  const unsigned short* Vh = (brx ? ATh : PTh) + (size_t)b * HH * SS;  // [512 h][128 t]
  const float* base = (brx ? Pbase : Abase) + (size_t)b * SS * HH;
  float* outp = (brx ? out2 : out1) + (size_t)b * SS * HH;
  unsigned short* Vs = (unsigned short*)(smem + 4608);  // 4 tiles [128][32], 8 KB each
  char* Vsb = smem + 4608;
  const int vrow = w * 32 + (L >> 2);
  const int afr2 = (L & 15) * 136;  // + kt*32 + (L>>4)*8

  for (int nc = 0; nc < 4; ++nc) {
    f32x4 pacc[2];
    pacc[0] = (f32x4)(0.0f);
    pacc[1] = (f32x4)(0.0f);
    const unsigned short* pV = Vh + (size_t)(nc * 128 + vrow) * SS + scol;
#pragma unroll
    for (int kt = 0; kt < 4; ++kt) {
      async16(pV + kt * 32, Vsb + kt * 8192 + laB);
      async16(pV + kt * 32 + 16 * SS, Vsb + kt * 8192 + laB + 1024);
    }
    __syncthreads();
#pragma unroll
    for (int kt = 0; kt < 4; ++kt) {
      bf16x8 pa = *(const bf16x8*)&attnHi[afr2 + kt * 32 + (L >> 4) * 8];
#pragma unroll
      for (int j = 0; j < 2; ++j) {
        bf16x8 pb = *(const bf16x8*)&Vs[kt * 4096 + bfr + j * 512];
        pacc[j] = __builtin_amdgcn_mfma_f32_16x16x32_bf16(pa, pb, pacc[j], 0, 0, 0);
      }
    }
    __syncthreads();
    if (q < 2) {
#pragma unroll
      for (int j = 0; j < 2; ++j) {
        const int hcol = nc * 128 + w * 32 + j * 16 + c;
#pragma unroll
        for (int r = 0; r < 4; ++r) {
          size_t o = (size_t)(rt * 8 + q * 4 + r) * HH + hcol;
          outp[o] = base[o] + pacc[j][r];
        }
      }
    }
  }
}

extern "C" void kernel_launch(void* const* d_in, const int* in_sizes, int n_in,
                              void* d_out, int out_size, void* d_ws, size_t ws_size,
                              hipStream_t stream) {
  const float* A  = (const float*)d_in[0];
  const float* P  = (const float*)d_in[1];
  const float* G1 = (const float*)d_in[2];
  const float* G2 = (const float*)d_in[3];
  const float* v1 = (const float*)d_in[4];
  const float* v2 = (const float*)d_in[5];
  float* out1 = (float*)d_out;
  float* out2 = out1 + (size_t)BB * SS * HH;

  const size_t NA = (size_t)BB * SS * HH;  // 2M
  const size_t NG = (size_t)HH * KC * HH;  // 2M
  unsigned short* Ahi = (unsigned short*)d_ws;
  unsigned short* Alo = Ahi + NA;
  unsigned short* Phi = Alo + NA;
  unsigned short* Plo = Phi + NA;
  unsigned short* G1h = Plo + NA;
  unsigned short* G1l = G1h + NG;
  unsigned short* G2h = G1l + NG;
  unsigned short* G2l = G2h + NG;
  unsigned short* ATh = G2l + NG;
  unsigned short* PTh = ATh + NA;
  unsigned short* dyn = PTh + NA;

  const size_t fixedBytes = (6 * NA + 4 * NG) * sizeof(unsigned short);  // 40 MB
  const size_t projPerB = (size_t)SS * NN;  // ushorts per batch per buffer
  const size_t perB = 4 * projPerB * sizeof(unsigned short);  // 4 MB/batch
  size_t rem = ws_size > fixedBytes ? ws_size - fixedBytes : 0;
  int Bc = (int)(rem / perB);
  if (Bc < 1) Bc = 1;
  if (Bc > BB) Bc = BB;
  unsigned short* prjH1 = dyn;
  unsigned short* prjL1 = prjH1 + (size_t)Bc * projPerB;
  unsigned short* prjH2 = prjL1 + (size_t)Bc * projPerB;
  unsigned short* prjL2 = prjH2 + (size_t)Bc * projPerB;

  convert_split2<<<dim3((unsigned)(NA / 1024), 1, 2), 256, 0, stream>>>(
      A, P, Ahi, Alo, Phi, Plo, (int)NA);
  convert_transpose_g<<<dim3(NN / 32, HH / 32, 2), 256, 0, stream>>>(
      G1, G2, G1h, G1l, G2h, G2l);
  convert_transpose_bh<<<dim3(HH / 32, (SS / 32) * BB, 2), 256, 0, stream>>>(
      A, P, ATh, PTh);

  for (int b0 = 0; b0 < BB; b0 += Bc) {
    int bc = (Bc < BB - b0) ? Bc : (BB - b0);
    size_t off = (size_t)b0 * SS * HH;  // element offset (both layouts)
    gemm_split<<<dim3(NN / 128, bc, 2), 256, 0, stream>>>(
        Ahi + off, Alo + off, G1h, G1l, G2h, G2l,
        prjH1, prjL1, prjH2, prjL2);
    attn_fused3<<<dim3(16, bc, 2), 256, 0, stream>>>(
        prjH1, prjL1, prjH2, prjL2,
        Phi + off, Plo + off, Ahi + off, Alo + off,
        PTh + off, ATh + off,
        A + off, P + off, v1, v2, out1 + off, out2 + off);
  }
}

// Round 6
// 254.019 us; speedup vs baseline: 2.5046x; 1.0472x over previous
//
#include <hip/hip_runtime.h>

// Problem constants: B=32, S=128, H=512, K=8
#define BB 32
#define SS 128
#define HH 512
#define KC 8
#define NN 4096  // KC*HH

typedef __attribute__((ext_vector_type(8))) short bf16x8;
typedef __attribute__((ext_vector_type(4))) float f32x4;

__device__ __forceinline__ unsigned short f2bf(float f) {
  unsigned int u = __float_as_uint(f);
  u += 0x7fffu + ((u >> 16) & 1u);   // round-to-nearest-even
  return (unsigned short)(u >> 16);
}
__device__ __forceinline__ float bf2f(unsigned short h) {
  return __uint_as_float(((unsigned int)h) << 16);
}
__device__ __forceinline__ float tanh_fast(float x) {
  float e = __expf(2.0f * x);
  return 1.0f - 2.0f / (e + 1.0f);
}
__device__ __forceinline__ void async16(const void* g, void* lds) {
  __builtin_amdgcn_global_load_lds(
      (const __attribute__((address_space(1))) unsigned int*)g,
      (__attribute__((address_space(3))) unsigned int*)lds, 16, 0, 0);
}

// ---- conversion kernels ---------------------------------------------------
__global__ __launch_bounds__(256) void convert_split2(
    const float* __restrict__ X0, const float* __restrict__ X1,
    unsigned short* __restrict__ h0, unsigned short* __restrict__ l0,
    unsigned short* __restrict__ h1, unsigned short* __restrict__ l1, int n) {
  const float* x = blockIdx.z ? X1 : X0;
  unsigned short* hi = blockIdx.z ? h1 : h0;
  unsigned short* lo = blockIdx.z ? l1 : l0;
  int i = (blockIdx.x * 256 + threadIdx.x) * 4;
  if (i >= n) return;
  float4 f = *(const float4*)&x[i];
  ushort4 h, l;
  h.x = f2bf(f.x); l.x = f2bf(f.x - bf2f(h.x));
  h.y = f2bf(f.y); l.y = f2bf(f.y - bf2f(h.y));
  h.z = f2bf(f.z); l.z = f2bf(f.z - bf2f(h.z));
  h.w = f2bf(f.w); l.w = f2bf(f.w - bf2f(h.w));
  *(ushort4*)&hi[i] = h;
  *(ushort4*)&lo[i] = l;
}

// G [512, 4096] fp32 -> G^T [4096, 512] (hi, lo) bf16; z selects G1/G2.
__global__ __launch_bounds__(256) void convert_transpose_g(
    const float* __restrict__ Ga, const float* __restrict__ Gb,
    unsigned short* __restrict__ ha, unsigned short* __restrict__ la,
    unsigned short* __restrict__ hb, unsigned short* __restrict__ lb) {
  const float* G = blockIdx.z ? Gb : Ga;
  unsigned short* hiT = blockIdx.z ? hb : ha;
  unsigned short* loT = blockIdx.z ? lb : la;
  __shared__ float t[32][33];
  const int bx = blockIdx.x * 32;  // n
  const int by = blockIdx.y * 32;  // k
  const int tx = threadIdx.x & 31, ty = threadIdx.x >> 5;
#pragma unroll
  for (int r = 0; r < 4; ++r)
    t[ty + r * 8][tx] = G[(size_t)(by + ty + r * 8) * NN + bx + tx];
  __syncthreads();
#pragma unroll
  for (int r = 0; r < 4; ++r) {
    float f = t[tx][ty + r * 8];
    size_t o = (size_t)(bx + ty + r * 8) * HH + by + tx;
    unsigned short h = f2bf(f);
    hiT[o] = h;
    loT[o] = f2bf(f - bf2f(h));
  }
}

// X [B,S,H] fp32 -> X^T [B,H,S] hi-only bf16 (PV V-operand); z selects A/P.
__global__ __launch_bounds__(256) void convert_transpose_bh(
    const float* __restrict__ Xa, const float* __restrict__ Xb,
    unsigned short* __restrict__ ha, unsigned short* __restrict__ hb) {
  const float* X = blockIdx.z ? Xb : Xa;
  unsigned short* hiT = blockIdx.z ? hb : ha;
  __shared__ float t[32][33];
  const int h0 = blockIdx.x * 32;
  const int s0 = (blockIdx.y & 3) * 32;
  const size_t b = blockIdx.y >> 2;
  const int tx = threadIdx.x & 31, ty = threadIdx.x >> 5;
#pragma unroll
  for (int r = 0; r < 4; ++r)
    t[ty + r * 8][tx] = X[b * (SS * HH) + (size_t)(s0 + ty + r * 8) * HH + h0 + tx];
  __syncthreads();
#pragma unroll
  for (int r = 0; r < 4; ++r) {
    float f = t[tx][ty + r * 8];
    size_t o = b * (SS * HH) + (size_t)(h0 + ty + r * 8) * SS + s0 + tx;
    hiT[o] = f2bf(f);
  }
}

// ---- 128x128x512 split-bf16 MFMA core (gemm_split only) -------------------
__device__ __forceinline__ void mm128_core(
    const unsigned short* __restrict__ Ah, const unsigned short* __restrict__ Al,
    const unsigned short* __restrict__ Bh, const unsigned short* __restrict__ Bl,
    unsigned short* sm, f32x4 acc[4][4]) {
  const int tid = threadIdx.x;
  const int w = tid >> 6, L = tid & 63;
  const int wm = w >> 1, wn = w & 1;
  char* smb = (char*)sm;
  const int srow = w * 32 + (L >> 2);
  const int scol = (L & 3) * 8;
  const unsigned short* pAh = Ah + (size_t)srow * HH + scol;
  const unsigned short* pAl = Al + (size_t)srow * HH + scol;
  const unsigned short* pBh = Bh + (size_t)srow * HH + scol;
  const unsigned short* pBl = Bl + (size_t)srow * HH + scol;
  const unsigned lbase = (unsigned)w * 2048;
  const int ar = (wm * 64 + (L & 15)) * 32 + (L >> 4) * 8;
  const int br = (wn * 64 + (L & 15)) * 32 + (L >> 4) * 8;

  for (int kt = 0; kt < 16; ++kt) {
    const int k0 = kt * 32;
    async16(pAh + k0, smb + lbase);
    async16(pAh + k0 + 16 * HH, smb + lbase + 1024);
    async16(pAl + k0, smb + 8192 + lbase);
    async16(pAl + k0 + 16 * HH, smb + 8192 + lbase + 1024);
    async16(pBh + k0, smb + 16384 + lbase);
    async16(pBh + k0 + 16 * HH, smb + 16384 + lbase + 1024);
    async16(pBl + k0, smb + 24576 + lbase);
    async16(pBl + k0 + 16 * HH, smb + 24576 + lbase + 1024);
    __syncthreads();
    bf16x8 ah[4], al[4], bh[4], bl[4];
#pragma unroll
    for (int i = 0; i < 4; ++i) {
      ah[i] = *(const bf16x8*)&sm[ar + i * 512];
      al[i] = *(const bf16x8*)&sm[4096 + ar + i * 512];
      bh[i] = *(const bf16x8*)&sm[8192 + br + i * 512];
      bl[i] = *(const bf16x8*)&sm[12288 + br + i * 512];
    }
#pragma unroll
    for (int i = 0; i < 4; ++i)
#pragma unroll
      for (int j = 0; j < 4; ++j) {
        acc[i][j] = __builtin_amdgcn_mfma_f32_16x16x32_bf16(ah[i], bh[j], acc[i][j], 0, 0, 0);
        acc[i][j] = __builtin_amdgcn_mfma_f32_16x16x32_bf16(ah[i], bl[j], acc[i][j], 0, 0, 0);
        acc[i][j] = __builtin_amdgcn_mfma_f32_16x16x32_bf16(al[i], bh[j], acc[i][j], 0, 0, 0);
      }
    __syncthreads();
  }
}

// ---- proj GEMM (both branches): C[M,4096] = A[M,512] @ G[512,4096] --------
__global__ __launch_bounds__(256) void gemm_split(
    const unsigned short* __restrict__ Ahi, const unsigned short* __restrict__ Alo,
    const unsigned short* __restrict__ G1h, const unsigned short* __restrict__ G1l,
    const unsigned short* __restrict__ G2h, const unsigned short* __restrict__ G2l,
    unsigned short* __restrict__ C1h, unsigned short* __restrict__ C1l,
    unsigned short* __restrict__ C2h, unsigned short* __restrict__ C2l) {
  __shared__ unsigned short sm[16384];
  const int bn = blockIdx.x * 128, bm = blockIdx.y * 128, brx = blockIdx.z;
  const unsigned short* Bh = (brx ? G2h : G1h) + (size_t)bn * HH;
  const unsigned short* Bl = (brx ? G2l : G1l) + (size_t)bn * HH;
  unsigned short* Ch = brx ? C2h : C1h;
  unsigned short* Cl = brx ? C2l : C1l;
  f32x4 acc[4][4];
#pragma unroll
  for (int i = 0; i < 4; ++i)
#pragma unroll
    for (int j = 0; j < 4; ++j) acc[i][j] = (f32x4)(0.0f);
  mm128_core(Ahi + (size_t)bm * HH, Alo + (size_t)bm * HH, Bh, Bl, sm, acc);
  const int tid = threadIdx.x, L = tid & 63, w = tid >> 6;
  const int wm = w >> 1, wn = w & 1;
  const int q = L >> 4, c = L & 15;
#pragma unroll
  for (int i = 0; i < 4; ++i)
#pragma unroll
    for (int j = 0; j < 4; ++j) {
      const int row = bm + wm * 64 + i * 16 + q * 4;
      const int col = bn + wn * 64 + j * 16 + c;
#pragma unroll
      for (int r = 0; r < 4; ++r) {
        float f = acc[i][j][r];
        unsigned short h = f2bf(f);
        size_t o = (size_t)(row + r) * NN + col;
        Ch[o] = h;
        Cl[o] = f2bf(f - bf2f(h));
      }
    }
}

// ---- fused attn: grid (bc*2 groups, 16 rt). Group = (b, branch) is the FAST
// grid dim -> the 16 rt-blocks of one group have linear ids == x (mod 64),
// hence land on the same XCD (round-robin dispatch) -> R/V stay in that
// XCD's L2 instead of thrashing to LLC/HBM. M=64 (8 s x 8 k) per block.
__global__ __launch_bounds__(256, 4) void attn_fused3(
    const unsigned short* __restrict__ P1h, const unsigned short* __restrict__ P1l,
    const unsigned short* __restrict__ P2h, const unsigned short* __restrict__ P2l,
    const unsigned short* __restrict__ R1h, const unsigned short* __restrict__ R1l,
    const unsigned short* __restrict__ R2h, const unsigned short* __restrict__ R2l,
    const unsigned short* __restrict__ PTh, const unsigned short* __restrict__ ATh,
    const float* __restrict__ Abase, const float* __restrict__ Pbase,
    const float* __restrict__ v1, const float* __restrict__ v2,
    float* __restrict__ out1, float* __restrict__ out2, int bc) {
  // [0,4352): attnHi [16][136] ushort. [4608, 37376): staging.
  __shared__ char smem[37376];
  const int x = blockIdx.x;
  const int brx = (x >= bc) ? 1 : 0;
  const int b = x - (brx ? bc : 0);
  const int rt = blockIdx.y;
  const int tid = threadIdx.x, w = tid >> 6, L = tid & 63;

  const unsigned short* Ah = (brx ? P2h : P1h) + ((size_t)b * 1024 + (size_t)rt * 64) * HH;
  const unsigned short* Al = (brx ? P2l : P1l) + ((size_t)b * 1024 + (size_t)rt * 64) * HH;
  const unsigned short* Bh = (brx ? R2h : R1h) + (size_t)b * SS * HH;
  const unsigned short* Bl = (brx ? R2l : R1l) + (size_t)b * SS * HH;
  const float* v = brx ? v2 : v1;

  unsigned short* cs = (unsigned short*)(smem + 4608);
  char* csb = smem + 4608;
  // ushort offsets within cs: Ahi [0,2048) Alo [2048,4096) Bhi [4096,8192) Blo [8192,12288)

  f32x4 acc[4][2];
#pragma unroll
  for (int i = 0; i < 4; ++i) { acc[i][0] = (f32x4)(0.0f); acc[i][1] = (f32x4)(0.0f); }

  const int scol = (L & 3) * 8;
  const unsigned short* pAh = Ah + (size_t)(w * 16 + (L >> 2)) * HH + scol;
  const unsigned short* pAl = Al + (size_t)(w * 16 + (L >> 2)) * HH + scol;
  const unsigned short* pBh = Bh + (size_t)(w * 32 + (L >> 2)) * HH + scol;
  const unsigned short* pBl = Bl + (size_t)(w * 32 + (L >> 2)) * HH + scol;
  const unsigned laA = (unsigned)w * 1024;
  const unsigned laB = (unsigned)w * 2048;
  const int afr = (L & 15) * 32 + (L >> 4) * 8;               // + i*512
  const int bfr = (w * 32 + (L & 15)) * 32 + (L >> 4) * 8;    // + j*512

  for (int kt = 0; kt < 16; ++kt) {
    const int k0 = kt * 32;
    async16(pAh + k0, csb + laA);
    async16(pAl + k0, csb + 4096 + laA);
    async16(pBh + k0, csb + 8192 + laB);
    async16(pBh + k0 + 16 * HH, csb + 8192 + laB + 1024);
    async16(pBl + k0, csb + 16384 + laB);
    async16(pBl + k0 + 16 * HH, csb + 16384 + laB + 1024);
    __syncthreads();
    bf16x8 ah[4], al[4], bhf[2], blf[2];
#pragma unroll
    for (int i = 0; i < 4; ++i) {
      ah[i] = *(const bf16x8*)&cs[afr + i * 512];
      al[i] = *(const bf16x8*)&cs[2048 + afr + i * 512];
    }
#pragma unroll
    for (int j = 0; j < 2; ++j) {
      bhf[j] = *(const bf16x8*)&cs[4096 + bfr + j * 512];
      blf[j] = *(const bf16x8*)&cs[8192 + bfr + j * 512];
    }
#pragma unroll
    for (int i = 0; i < 4; ++i)
#pragma unroll
      for (int j = 0; j < 2; ++j) {
        acc[i][j] = __builtin_amdgcn_mfma_f32_16x16x32_bf16(ah[i], bhf[j], acc[i][j], 0, 0, 0);
        acc[i][j] = __builtin_amdgcn_mfma_f32_16x16x32_bf16(ah[i], blf[j], acc[i][j], 0, 0, 0);
        acc[i][j] = __builtin_amdgcn_mfma_f32_16x16x32_bf16(al[i], bhf[j], acc[i][j], 0, 0, 0);
      }
    __syncthreads();
  }

  // ---- tanh + k-combine -> scoresS[8][132] (aliases staging region) ----
  float (*scoresS)[132] = (float(*)[132])(smem + 4608);
  unsigned short* attnHi = (unsigned short*)smem;  // [16][136]
  const int q = L >> 4, c = L & 15;
  float vk[KC];
#pragma unroll
  for (int k = 0; k < KC; ++k) vk[k] = v[k];
  // C row = i*16 + q*4 + r = s_loc*8 + k with k=(q&1)*4+r, s_loc=i*2+(q>>1)
#pragma unroll
  for (int i = 0; i < 4; ++i)
#pragma unroll
    for (int j = 0; j < 2; ++j) {
      float part = 0.0f;
#pragma unroll
      for (int r = 0; r < 4; ++r)
        part = fmaf(vk[(q & 1) * 4 + r], tanh_fast(acc[i][j][r]), part);
      part += __shfl_xor(part, 16);  // combine k halves (q ^ 1)
      if ((q & 1) == 0)
        scoresS[i * 2 + (q >> 1)][w * 32 + j * 16 + c] = part;
    }
  __syncthreads();

  // ---- softmax: 8 s-rows x 128 t, 32 threads/row ----
  const int ty = tid >> 5, tx = tid & 31;
  float sc[4];
#pragma unroll
  for (int j = 0; j < 4; ++j) sc[j] = scoresS[ty][tx * 4 + j];
  float mx = fmaxf(fmaxf(sc[0], sc[1]), fmaxf(sc[2], sc[3]));
#pragma unroll
  for (int off = 1; off < 32; off <<= 1) mx = fmaxf(mx, __shfl_xor(mx, off, 32));
  float p[4], ssum = 0.0f;
#pragma unroll
  for (int j = 0; j < 4; ++j) { p[j] = __expf(sc[j] - mx); ssum += p[j]; }
#pragma unroll
  for (int off = 1; off < 32; off <<= 1) ssum += __shfl_xor(ssum, off, 32);
  float inv = 1.0f / ssum;
  ushort4 hq;
  hq.x = f2bf(p[0] * inv); hq.y = f2bf(p[1] * inv);
  hq.z = f2bf(p[2] * inv); hq.w = f2bf(p[3] * inv);
  *(ushort4*)&attnHi[ty * 136 + tx * 4] = hq;
  __syncthreads();  // attn written; staging region free for V tiles

  // ---- PV hi-only: out[8 x 512] = base + attn[8x128] @ V[128x512] ----
  const unsigned short* Vh = (brx ? ATh : PTh) + (size_t)b * HH * SS;  // [512 h][128 t]
  const float* base = (brx ? Pbase : Abase) + (size_t)b * SS * HH;
  float* outp = (brx ? out2 : out1) + (size_t)b * SS * HH;
  unsigned short* Vs = (unsigned short*)(smem + 4608);  // 4 tiles [128][32], 8 KB each
  char* Vsb = smem + 4608;
  const int vrow = w * 32 + (L >> 2);
  const int afr2 = (L & 15) * 136;  // + kt*32 + (L>>4)*8

  for (int nc = 0; nc < 4; ++nc) {
    f32x4 pacc[2];
    pacc[0] = (f32x4)(0.0f);
    pacc[1] = (f32x4)(0.0f);
    const unsigned short* pV = Vh + (size_t)(nc * 128 + vrow) * SS + scol;
#pragma unroll
    for (int kt = 0; kt < 4; ++kt) {
      async16(pV + kt * 32, Vsb + kt * 8192 + laB);
      async16(pV + kt * 32 + 16 * SS, Vsb + kt * 8192 + laB + 1024);
    }
    __syncthreads();
#pragma unroll
    for (int kt = 0; kt < 4; ++kt) {
      bf16x8 pa = *(const bf16x8*)&attnHi[afr2 + kt * 32 + (L >> 4) * 8];
#pragma unroll
      for (int j = 0; j < 2; ++j) {
        bf16x8 pb = *(const bf16x8*)&Vs[kt * 4096 + bfr + j * 512];
        pacc[j] = __builtin_amdgcn_mfma_f32_16x16x32_bf16(pa, pb, pacc[j], 0, 0, 0);
      }
    }
    __syncthreads();
    if (q < 2) {
#pragma unroll
      for (int j = 0; j < 2; ++j) {
        const int hcol = nc * 128 + w * 32 + j * 16 + c;
#pragma unroll
        for (int r = 0; r < 4; ++r) {
          size_t o = (size_t)(rt * 8 + q * 4 + r) * HH + hcol;
          outp[o] = base[o] + pacc[j][r];
        }
      }
    }
  }
}

extern "C" void kernel_launch(void* const* d_in, const int* in_sizes, int n_in,
                              void* d_out, int out_size, void* d_ws, size_t ws_size,
                              hipStream_t stream) {
  const float* A  = (const float*)d_in[0];
  const float* P  = (const float*)d_in[1];
  const float* G1 = (const float*)d_in[2];
  const float* G2 = (const float*)d_in[3];
  const float* v1 = (const float*)d_in[4];
  const float* v2 = (const float*)d_in[5];
  float* out1 = (float*)d_out;
  float* out2 = out1 + (size_t)BB * SS * HH;

  const size_t NA = (size_t)BB * SS * HH;  // 2M
  const size_t NG = (size_t)HH * KC * HH;  // 2M
  unsigned short* Ahi = (unsigned short*)d_ws;
  unsigned short* Alo = Ahi + NA;
  unsigned short* Phi = Alo + NA;
  unsigned short* Plo = Phi + NA;
  unsigned short* G1h = Plo + NA;
  unsigned short* G1l = G1h + NG;
  unsigned short* G2h = G1l + NG;
  unsigned short* G2l = G2h + NG;
  unsigned short* ATh = G2l + NG;
  unsigned short* PTh = ATh + NA;
  unsigned short* dyn = PTh + NA;

  const size_t fixedBytes = (6 * NA + 4 * NG) * sizeof(unsigned short);  // 40 MB
  const size_t projPerB = (size_t)SS * NN;  // ushorts per batch per buffer
  const size_t perB = 4 * projPerB * sizeof(unsigned short);  // 4 MB/batch
  size_t rem = ws_size > fixedBytes ? ws_size - fixedBytes : 0;
  int Bc = (int)(rem / perB);
  if (Bc < 1) Bc = 1;
  if (Bc > BB) Bc = BB;
  unsigned short* prjH1 = dyn;
  unsigned short* prjL1 = prjH1 + (size_t)Bc * projPerB;
  unsigned short* prjH2 = prjL1 + (size_t)Bc * projPerB;
  unsigned short* prjL2 = prjH2 + (size_t)Bc * projPerB;

  convert_split2<<<dim3((unsigned)(NA / 1024), 1, 2), 256, 0, stream>>>(
      A, P, Ahi, Alo, Phi, Plo, (int)NA);
  convert_transpose_g<<<dim3(NN / 32, HH / 32, 2), 256, 0, stream>>>(
      G1, G2, G1h, G1l, G2h, G2l);
  convert_transpose_bh<<<dim3(HH / 32, (SS / 32) * BB, 2), 256, 0, stream>>>(
      A, P, ATh, PTh);

  for (int b0 = 0; b0 < BB; b0 += Bc) {
    int bc = (Bc < BB - b0) ? Bc : (BB - b0);
    size_t off = (size_t)b0 * SS * HH;  // element offset (both layouts)
    gemm_split<<<dim3(NN / 128, bc, 2), 256, 0, stream>>>(
        Ahi + off, Alo + off, G1h, G1l, G2h, G2l,
        prjH1, prjL1, prjH2, prjL2);
    // grid: x = (b, branch) group [fast -> XCD-pinned], y = rt
    attn_fused3<<<dim3(bc * 2, 16), 256, 0, stream>>>(
        prjH1, prjL1, prjH2, prjL2,
        Phi + off, Plo + off, Ahi + off, Alo + off,
        PTh + off, ATh + off,
        A + off, P + off, v1, v2, out1 + off, out2 + off, bc);
  }
}

// Round 7
// 252.652 us; speedup vs baseline: 2.5182x; 1.0054x over previous
//
#include <hip/hip_runtime.h>

// Problem constants: B=32, S=128, H=512, K=8
#define BB 32
#define SS 128
#define HH 512
#define KC 8
#define NN 4096  // KC*HH

typedef __attribute__((ext_vector_type(8))) short bf16x8;
typedef __attribute__((ext_vector_type(4))) float f32x4;

__device__ __forceinline__ unsigned short f2bf(float f) {
  unsigned int u = __float_as_uint(f);
  u += 0x7fffu + ((u >> 16) & 1u);   // round-to-nearest-even
  return (unsigned short)(u >> 16);
}
__device__ __forceinline__ float bf2f(unsigned short h) {
  return __uint_as_float(((unsigned int)h) << 16);
}
__device__ __forceinline__ float tanh_fast(float x) {
  float e = __expf(2.0f * x);
  return 1.0f - 2.0f / (e + 1.0f);
}
__device__ __forceinline__ void async16(const void* g, void* lds) {
  __builtin_amdgcn_global_load_lds(
      (const __attribute__((address_space(1))) unsigned int*)g,
      (__attribute__((address_space(3))) unsigned int*)lds, 16, 0, 0);
}

// ---- conversion kernels ---------------------------------------------------
// A/P: fp32 [B,S,H] -> hi/lo row-major AND hi-only transposed [B,H,S], one read.
__global__ __launch_bounds__(256) void convert_ap(
    const float* __restrict__ Xa, const float* __restrict__ Xb,
    unsigned short* __restrict__ hia, unsigned short* __restrict__ loa,
    unsigned short* __restrict__ hiTa,
    unsigned short* __restrict__ hib, unsigned short* __restrict__ lob,
    unsigned short* __restrict__ hiTb) {
  const float* X = blockIdx.z ? Xb : Xa;
  unsigned short* hi = blockIdx.z ? hib : hia;
  unsigned short* lo = blockIdx.z ? lob : loa;
  unsigned short* hiT = blockIdx.z ? hiTb : hiTa;
  __shared__ float t[32][33];
  const int h0 = blockIdx.x * 32;
  const int s0 = (blockIdx.y & 3) * 32;
  const size_t b = blockIdx.y >> 2;
  const int tx = threadIdx.x & 31, ty = threadIdx.x >> 5;
#pragma unroll
  for (int r = 0; r < 4; ++r) {
    float f = X[b * (SS * HH) + (size_t)(s0 + ty + r * 8) * HH + h0 + tx];
    t[ty + r * 8][tx] = f;
    size_t o = b * (SS * HH) + (size_t)(s0 + ty + r * 8) * HH + h0 + tx;
    unsigned short h = f2bf(f);
    hi[o] = h;
    lo[o] = f2bf(f - bf2f(h));
  }
  __syncthreads();
#pragma unroll
  for (int r = 0; r < 4; ++r) {
    float f = t[tx][ty + r * 8];
    size_t o = b * (SS * HH) + (size_t)(h0 + ty + r * 8) * SS + s0 + tx;
    hiT[o] = f2bf(f);
  }
}

// G [512, 4096] fp32 -> G^T [4096, 512] (hi, lo) bf16; z selects G1/G2.
__global__ __launch_bounds__(256) void convert_transpose_g(
    const float* __restrict__ Ga, const float* __restrict__ Gb,
    unsigned short* __restrict__ ha, unsigned short* __restrict__ la,
    unsigned short* __restrict__ hb, unsigned short* __restrict__ lb) {
  const float* G = blockIdx.z ? Gb : Ga;
  unsigned short* hiT = blockIdx.z ? hb : ha;
  unsigned short* loT = blockIdx.z ? lb : la;
  __shared__ float t[32][33];
  const int bx = blockIdx.x * 32;  // n
  const int by = blockIdx.y * 32;  // k
  const int tx = threadIdx.x & 31, ty = threadIdx.x >> 5;
#pragma unroll
  for (int r = 0; r < 4; ++r)
    t[ty + r * 8][tx] = G[(size_t)(by + ty + r * 8) * NN + bx + tx];
  __syncthreads();
#pragma unroll
  for (int r = 0; r < 4; ++r) {
    float f = t[tx][ty + r * 8];
    size_t o = (size_t)(bx + ty + r * 8) * HH + by + tx;
    unsigned short h = f2bf(f);
    hiT[o] = h;
    loT[o] = f2bf(f - bf2f(h));
  }
}

// ---- 128x128x512 split-bf16 MFMA core (gemm_split) ------------------------
__device__ __forceinline__ void mm128_core(
    const unsigned short* __restrict__ Ah, const unsigned short* __restrict__ Al,
    const unsigned short* __restrict__ Bh, const unsigned short* __restrict__ Bl,
    unsigned short* sm, f32x4 acc[4][4]) {
  const int tid = threadIdx.x;
  const int w = tid >> 6, L = tid & 63;
  const int wm = w >> 1, wn = w & 1;
  char* smb = (char*)sm;
  const int srow = w * 32 + (L >> 2);
  const int scol = (L & 3) * 8;
  const unsigned short* pAh = Ah + (size_t)srow * HH + scol;
  const unsigned short* pAl = Al + (size_t)srow * HH + scol;
  const unsigned short* pBh = Bh + (size_t)srow * HH + scol;
  const unsigned short* pBl = Bl + (size_t)srow * HH + scol;
  const unsigned lbase = (unsigned)w * 2048;
  const int ar = (wm * 64 + (L & 15)) * 32 + (L >> 4) * 8;
  const int br = (wn * 64 + (L & 15)) * 32 + (L >> 4) * 8;

  for (int kt = 0; kt < 16; ++kt) {
    const int k0 = kt * 32;
    async16(pAh + k0, smb + lbase);
    async16(pAh + k0 + 16 * HH, smb + lbase + 1024);
    async16(pAl + k0, smb + 8192 + lbase);
    async16(pAl + k0 + 16 * HH, smb + 8192 + lbase + 1024);
    async16(pBh + k0, smb + 16384 + lbase);
    async16(pBh + k0 + 16 * HH, smb + 16384 + lbase + 1024);
    async16(pBl + k0, smb + 24576 + lbase);
    async16(pBl + k0 + 16 * HH, smb + 24576 + lbase + 1024);
    __syncthreads();
    bf16x8 ah[4], al[4], bh[4], bl[4];
#pragma unroll
    for (int i = 0; i < 4; ++i) {
      ah[i] = *(const bf16x8*)&sm[ar + i * 512];
      al[i] = *(const bf16x8*)&sm[4096 + ar + i * 512];
      bh[i] = *(const bf16x8*)&sm[8192 + br + i * 512];
      bl[i] = *(const bf16x8*)&sm[12288 + br + i * 512];
    }
#pragma unroll
    for (int i = 0; i < 4; ++i)
#pragma unroll
      for (int j = 0; j < 4; ++j) {
        acc[i][j] = __builtin_amdgcn_mfma_f32_16x16x32_bf16(ah[i], bh[j], acc[i][j], 0, 0, 0);
        acc[i][j] = __builtin_amdgcn_mfma_f32_16x16x32_bf16(ah[i], bl[j], acc[i][j], 0, 0, 0);
        acc[i][j] = __builtin_amdgcn_mfma_f32_16x16x32_bf16(al[i], bh[j], acc[i][j], 0, 0, 0);
      }
    __syncthreads();
  }
}

// ---- proj GEMM (both branches): C[M,4096] = A[M,512] @ G[512,4096] --------
__global__ __launch_bounds__(256) void gemm_split(
    const unsigned short* __restrict__ Ahi, const unsigned short* __restrict__ Alo,
    const unsigned short* __restrict__ G1h, const unsigned short* __restrict__ G1l,
    const unsigned short* __restrict__ G2h, const unsigned short* __restrict__ G2l,
    unsigned short* __restrict__ C1h, unsigned short* __restrict__ C1l,
    unsigned short* __restrict__ C2h, unsigned short* __restrict__ C2l) {
  __shared__ unsigned short sm[16384];
  const int bn = blockIdx.x * 128, bm = blockIdx.y * 128, brx = blockIdx.z;
  const unsigned short* Bh = (brx ? G2h : G1h) + (size_t)bn * HH;
  const unsigned short* Bl = (brx ? G2l : G1l) + (size_t)bn * HH;
  unsigned short* Ch = brx ? C2h : C1h;
  unsigned short* Cl = brx ? C2l : C1l;
  f32x4 acc[4][4];
#pragma unroll
  for (int i = 0; i < 4; ++i)
#pragma unroll
    for (int j = 0; j < 4; ++j) acc[i][j] = (f32x4)(0.0f);
  mm128_core(Ahi + (size_t)bm * HH, Alo + (size_t)bm * HH, Bh, Bl, sm, acc);
  const int tid = threadIdx.x, L = tid & 63, w = tid >> 6;
  const int wm = w >> 1, wn = w & 1;
  const int q = L >> 4, c = L & 15;
#pragma unroll
  for (int i = 0; i < 4; ++i)
#pragma unroll
    for (int j = 0; j < 4; ++j) {
      const int row = bm + wm * 64 + i * 16 + q * 4;
      const int col = bn + wn * 64 + j * 16 + c;
#pragma unroll
      for (int r = 0; r < 4; ++r) {
        float f = acc[i][j][r];
        unsigned short h = f2bf(f);
        size_t o = (size_t)(row + r) * NN + col;
        Ch[o] = h;
        Cl[o] = f2bf(f - bf2f(h));
      }
    }
}

// ---- score kernel: M=128 (16 s x 8 k), N=128 t, K=512 g, double-buffered --
// Pipelined staging: iter kt issues buf[kt+1]'s 8 async16, then waits
// vmcnt(8) (kt's loads done, kt+1's in flight) + raw s_barrier -> loads
// overlap MFMA across the barrier. Output: softmaxed attn weights (bf16 hi)
// to global attnW[group][s][t].
__global__ __launch_bounds__(256, 2) void attn_score4(
    const unsigned short* __restrict__ P1h, const unsigned short* __restrict__ P1l,
    const unsigned short* __restrict__ P2h, const unsigned short* __restrict__ P2l,
    const unsigned short* __restrict__ R1h, const unsigned short* __restrict__ R1l,
    const unsigned short* __restrict__ R2h, const unsigned short* __restrict__ R2l,
    const float* __restrict__ v1, const float* __restrict__ v2,
    unsigned short* __restrict__ attnW, int bc) {
  __shared__ char smem[65536];  // two 32 KB staging buffers
  unsigned short* sm = (unsigned short*)smem;
  const int x = blockIdx.x;
  const int brx = (x >= bc) ? 1 : 0;
  const int b = x - (brx ? bc : 0);
  const int rt = blockIdx.y;
  const int tid = threadIdx.x, w = tid >> 6, L = tid & 63;
  const int wm = w >> 1, wn = w & 1;

  const unsigned short* Ah = (brx ? P2h : P1h) + ((size_t)b * 1024 + (size_t)rt * 128) * HH;
  const unsigned short* Al = (brx ? P2l : P1l) + ((size_t)b * 1024 + (size_t)rt * 128) * HH;
  const unsigned short* Bh = (brx ? R2h : R1h) + (size_t)b * SS * HH;
  const unsigned short* Bl = (brx ? R2l : R1l) + (size_t)b * SS * HH;

  const int srow = w * 32 + (L >> 2);
  const int scol = (L & 3) * 8;
  const unsigned short* pAh = Ah + (size_t)srow * HH + scol;
  const unsigned short* pAl = Al + (size_t)srow * HH + scol;
  const unsigned short* pBh = Bh + (size_t)srow * HH + scol;
  const unsigned short* pBl = Bl + (size_t)srow * HH + scol;
  const unsigned lbase = (unsigned)w * 2048;
  const int ar = (wm * 64 + (L & 15)) * 32 + (L >> 4) * 8;
  const int br = (wn * 64 + (L & 15)) * 32 + (L >> 4) * 8;

  f32x4 acc[4][4];
#pragma unroll
  for (int i = 0; i < 4; ++i)
#pragma unroll
    for (int j = 0; j < 4; ++j) acc[i][j] = (f32x4)(0.0f);

  // prologue: stage kt=0 into buf0
  {
    char* d = smem;
    async16(pAh, d + lbase);
    async16(pAh + 16 * HH, d + lbase + 1024);
    async16(pAl, d + 8192 + lbase);
    async16(pAl + 16 * HH, d + 8192 + lbase + 1024);
    async16(pBh, d + 16384 + lbase);
    async16(pBh + 16 * HH, d + 16384 + lbase + 1024);
    async16(pBl, d + 24576 + lbase);
    async16(pBl + 16 * HH, d + 24576 + lbase + 1024);
  }
  for (int kt = 0; kt < 16; ++kt) {
    if (kt + 1 < 16) {
      const int k0 = (kt + 1) * 32;
      char* d = smem + ((kt + 1) & 1) * 32768;
      async16(pAh + k0, d + lbase);
      async16(pAh + k0 + 16 * HH, d + lbase + 1024);
      async16(pAl + k0, d + 8192 + lbase);
      async16(pAl + k0 + 16 * HH, d + 8192 + lbase + 1024);
      async16(pBh + k0, d + 16384 + lbase);
      async16(pBh + k0 + 16 * HH, d + 16384 + lbase + 1024);
      async16(pBl + k0, d + 24576 + lbase);
      async16(pBl + k0 + 16 * HH, d + 24576 + lbase + 1024);
      asm volatile("s_waitcnt vmcnt(8) lgkmcnt(0)" ::: "memory");
    } else {
      asm volatile("s_waitcnt vmcnt(0) lgkmcnt(0)" ::: "memory");
    }
    asm volatile("s_barrier" ::: "memory");
    const unsigned short* cb = sm + (kt & 1) * 16384;
    bf16x8 ah[4], al[4], bh[4], bl[4];
#pragma unroll
    for (int i = 0; i < 4; ++i) {
      ah[i] = *(const bf16x8*)&cb[ar + i * 512];
      al[i] = *(const bf16x8*)&cb[4096 + ar + i * 512];
      bh[i] = *(const bf16x8*)&cb[8192 + br + i * 512];
      bl[i] = *(const bf16x8*)&cb[12288 + br + i * 512];
    }
#pragma unroll
    for (int i = 0; i < 4; ++i)
#pragma unroll
      for (int j = 0; j < 4; ++j) {
        acc[i][j] = __builtin_amdgcn_mfma_f32_16x16x32_bf16(ah[i], bh[j], acc[i][j], 0, 0, 0);
        acc[i][j] = __builtin_amdgcn_mfma_f32_16x16x32_bf16(ah[i], bl[j], acc[i][j], 0, 0, 0);
        acc[i][j] = __builtin_amdgcn_mfma_f32_16x16x32_bf16(al[i], bh[j], acc[i][j], 0, 0, 0);
      }
  }
  __syncthreads();  // full drain before aliasing staging as scoresS

  // ---- tanh + k-combine -> scoresS[16][132] ----
  float (*scoresS)[132] = (float(*)[132])smem;
  const int q = L >> 4, c = L & 15;
  const float* v = brx ? v2 : v1;
  float vk[KC];
#pragma unroll
  for (int k = 0; k < KC; ++k) vk[k] = v[k];
  // C row = wm*64 + i*16 + q*4 + r = s_loc*8 + k; k=(q&1)*4+r, s_loc=wm*8+i*2+(q>>1)
#pragma unroll
  for (int i = 0; i < 4; ++i)
#pragma unroll
    for (int j = 0; j < 4; ++j) {
      float part = 0.0f;
#pragma unroll
      for (int r = 0; r < 4; ++r)
        part = fmaf(vk[(q & 1) * 4 + r], tanh_fast(acc[i][j][r]), part);
      part += __shfl_xor(part, 16);  // combine k halves
      if ((q & 1) == 0)
        scoresS[wm * 8 + i * 2 + (q >> 1)][wn * 64 + j * 16 + c] = part;
    }
  __syncthreads();

  // ---- softmax over t (128), 16 threads per s-row; write attnW global ----
  const int tx = tid & 15, ty = tid >> 4;
  float sc[8];
#pragma unroll
  for (int j = 0; j < 8; ++j) sc[j] = scoresS[ty][tx * 8 + j];
  float mx = sc[0];
#pragma unroll
  for (int j = 1; j < 8; ++j) mx = fmaxf(mx, sc[j]);
#pragma unroll
  for (int off = 1; off < 16; off <<= 1) mx = fmaxf(mx, __shfl_xor(mx, off, 16));
  float p[8], ssum = 0.0f;
#pragma unroll
  for (int j = 0; j < 8; ++j) { p[j] = __expf(sc[j] - mx); ssum += p[j]; }
#pragma unroll
  for (int off = 1; off < 16; off <<= 1) ssum += __shfl_xor(ssum, off, 16);
  float inv = 1.0f / ssum;
  ushort4 h0, h1;
  h0.x = f2bf(p[0] * inv); h0.y = f2bf(p[1] * inv);
  h0.z = f2bf(p[2] * inv); h0.w = f2bf(p[3] * inv);
  h1.x = f2bf(p[4] * inv); h1.y = f2bf(p[5] * inv);
  h1.z = f2bf(p[6] * inv); h1.w = f2bf(p[7] * inv);
  size_t abase = (size_t)x * (SS * SS) + (size_t)(rt * 16 + ty) * SS + tx * 8;
  *(ushort4*)&attnW[abase] = h0;
  *(ushort4*)&attnW[abase + 4] = h1;
}

// ---- PV + residual: out[64 s x 128 h] = base + attn[64x128] @ V[128x128] --
// grid (bc*2 groups, 8): y -> hc = y&3 (h chunk), sh = y>>2 (s half).
__global__ __launch_bounds__(256) void pv_res2(
    const unsigned short* __restrict__ attnW,
    const unsigned short* __restrict__ PTh, const unsigned short* __restrict__ ATh,
    const float* __restrict__ Abase, const float* __restrict__ Pbase,
    float* __restrict__ out1, float* __restrict__ out2, int bc) {
  __shared__ char smem[12288];  // A [64][32] 4 KB | B [128][32] 8 KB
  unsigned short* sm = (unsigned short*)smem;
  const int x = blockIdx.x;
  const int brx = (x >= bc) ? 1 : 0;
  const int b = x - (brx ? bc : 0);
  const int hc = blockIdx.y & 3, sh = blockIdx.y >> 2;
  const int tid = threadIdx.x, w = tid >> 6, L = tid & 63;
  const int wm = w >> 1, wn = w & 1;

  const unsigned short* Aw = attnW + (size_t)x * (SS * SS) + (size_t)(sh * 64) * SS;
  const unsigned short* Vh = (brx ? ATh : PTh) + (size_t)b * HH * SS + (size_t)(hc * 128) * SS;
  const float* base = (brx ? Pbase : Abase) + (size_t)b * SS * HH;
  float* outp = (brx ? out2 : out1) + (size_t)b * SS * HH;

  f32x4 acc[2][4];
#pragma unroll
  for (int i = 0; i < 2; ++i)
#pragma unroll
    for (int j = 0; j < 4; ++j) acc[i][j] = (f32x4)(0.0f);

  const int arow = w * 16 + (L >> 2);          // A stage row (0..63)
  const int brow = w * 32 + (L >> 2);          // B stage rows (0..127), +16
  const int scol = (L & 3) * 8;
  const int afr = (wm * 32 + (L & 15)) * 32 + (L >> 4) * 8;         // + i*512
  const int bfr = 2048 + (wn * 64 + (L & 15)) * 32 + (L >> 4) * 8;  // + j*512

  for (int kt = 0; kt < 4; ++kt) {
    const int k0 = kt * 32;
    async16(Aw + (size_t)arow * SS + k0 + scol, smem + w * 1024);
    async16(Vh + (size_t)brow * SS + k0 + scol, smem + 4096 + w * 2048);
    async16(Vh + (size_t)(brow + 16) * SS + k0 + scol, smem + 4096 + w * 2048 + 1024);
    __syncthreads();
    bf16x8 af[2], bf[4];
#pragma unroll
    for (int i = 0; i < 2; ++i) af[i] = *(const bf16x8*)&sm[afr + i * 512];
#pragma unroll
    for (int j = 0; j < 4; ++j) bf[j] = *(const bf16x8*)&sm[bfr + j * 512];
#pragma unroll
    for (int i = 0; i < 2; ++i)
#pragma unroll
      for (int j = 0; j < 4; ++j)
        acc[i][j] = __builtin_amdgcn_mfma_f32_16x16x32_bf16(af[i], bf[j], acc[i][j], 0, 0, 0);
    __syncthreads();
  }

  const int q = L >> 4, c = L & 15;
#pragma unroll
  for (int i = 0; i < 2; ++i)
#pragma unroll
    for (int j = 0; j < 4; ++j) {
      const int srow = sh * 64 + wm * 32 + i * 16 + q * 4;   // s
      const int hcol = hc * 128 + wn * 64 + j * 16 + c;      // h
#pragma unroll
      for (int r = 0; r < 4; ++r) {
        size_t o = (size_t)(srow + r) * HH + hcol;
        outp[o] = base[o] + acc[i][j][r];
      }
    }
}

extern "C" void kernel_launch(void* const* d_in, const int* in_sizes, int n_in,
                              void* d_out, int out_size, void* d_ws, size_t ws_size,
                              hipStream_t stream) {
  const float* A  = (const float*)d_in[0];
  const float* P  = (const float*)d_in[1];
  const float* G1 = (const float*)d_in[2];
  const float* G2 = (const float*)d_in[3];
  const float* v1 = (const float*)d_in[4];
  const float* v2 = (const float*)d_in[5];
  float* out1 = (float*)d_out;
  float* out2 = out1 + (size_t)BB * SS * HH;

  const size_t NA = (size_t)BB * SS * HH;  // 2M
  const size_t NG = (size_t)HH * KC * HH;  // 2M
  unsigned short* Ahi = (unsigned short*)d_ws;
  unsigned short* Alo = Ahi + NA;
  unsigned short* Phi = Alo + NA;
  unsigned short* Plo = Phi + NA;
  unsigned short* G1h = Plo + NA;
  unsigned short* G1l = G1h + NG;
  unsigned short* G2h = G1l + NG;
  unsigned short* G2l = G2h + NG;
  unsigned short* ATh = G2l + NG;
  unsigned short* PTh = ATh + NA;
  unsigned short* dyn = PTh + NA;

  const size_t fixedBytes = (6 * NA + 4 * NG) * sizeof(unsigned short);  // 40 MB
  const size_t projPerB = (size_t)SS * NN;        // ushorts/batch/buffer
  const size_t attnPerB = 2 * (size_t)SS * SS;    // ushorts/batch (both branches)
  const size_t perB = (4 * projPerB + attnPerB) * sizeof(unsigned short);
  size_t rem = ws_size > fixedBytes ? ws_size - fixedBytes : 0;
  int Bc = (int)(rem / perB);
  if (Bc < 1) Bc = 1;
  if (Bc > BB) Bc = BB;
  unsigned short* prjH1 = dyn;
  unsigned short* prjL1 = prjH1 + (size_t)Bc * projPerB;
  unsigned short* prjH2 = prjL1 + (size_t)Bc * projPerB;
  unsigned short* prjL2 = prjH2 + (size_t)Bc * projPerB;
  unsigned short* attnW = prjL2 + (size_t)Bc * projPerB;

  convert_ap<<<dim3(HH / 32, (SS / 32) * BB, 2), 256, 0, stream>>>(
      A, P, Ahi, Alo, ATh, Phi, Plo, PTh);
  convert_transpose_g<<<dim3(NN / 32, HH / 32, 2), 256, 0, stream>>>(
      G1, G2, G1h, G1l, G2h, G2l);

  for (int b0 = 0; b0 < BB; b0 += Bc) {
    int bc = (Bc < BB - b0) ? Bc : (BB - b0);
    size_t off = (size_t)b0 * SS * HH;  // element offset (both layouts)
    gemm_split<<<dim3(NN / 128, bc, 2), 256, 0, stream>>>(
        Ahi + off, Alo + off, G1h, G1l, G2h, G2l,
        prjH1, prjL1, prjH2, prjL2);
    // Branch 1: scores vs P; branch 2: scores vs A (faithful to source).
    attn_score4<<<dim3(bc * 2, 8), 256, 0, stream>>>(
        prjH1, prjL1, prjH2, prjL2,
        Phi + off, Plo + off, Ahi + off, Alo + off,
        v1, v2, attnW, bc);
    // out1 = A + attn1 @ P (V = PTh); out2 = P + attn2 @ A (V = ATh)
    pv_res2<<<dim3(bc * 2, 8), 256, 0, stream>>>(
        attnW, PTh + off, ATh + off, A + off, P + off,
        out1 + off, out2 + off, bc);
  }
}